// Round 1
// 543.280 us; speedup vs baseline: 1.0302x; 1.0302x over previous
//
#include <hip/hip_runtime.h>
#include <hip/hip_bf16.h>
#include <cstdint>

// ---------------------------------------------------------------------------
// LinearAttention on MI355X (gfx950)
// L=4096, N=4, E=1024, H=16, D=64.  M = L*N = 16384.
// Round 5: double-buffered K-loop (T3-minimum 2-phase). BK=32 tiles in two
// 16KB LDS buffer pairs (same verified conflict-free layout, same 32KB total);
// loop unrolled x2 so buffer offsets are compile-time constants. Each
// iteration issues the NEXT tile's global_load_lds BEFORE computing the
// current tile, so the vmcnt(0) drain at the barrier overlaps the 16-MFMA
// phase instead of preceding it. Diagnosed regime: 16% MfmaUtil / 17% HBM /
// ~1.9 blocks/CU -> latency-serialized, per-iter cost = load-drain + MFMA
// summed (3150 cyc vs ~1400 steady-state equivalent).
// Epilogue (LDS-staged packed stores) and all other kernels unchanged.
// ---------------------------------------------------------------------------

typedef __attribute__((ext_vector_type(8))) short bf16x8;
typedef __attribute__((ext_vector_type(4))) float f32x4;

#define L_SEQ 4096
#define NBATCH 4
#define EMB 1024
#define NHEADS 16
#define HDIM 64
#define MROWS (L_SEQ * NBATCH)   // 16384
#define NHG (NBATCH * NHEADS)    // 64 head-groups
#define LCHUNK 512
#define NCHUNK (L_SEQ / LCHUNK)  // 8

__device__ __forceinline__ unsigned short f2bf(float f) {
  union { float f; uint32_t u; } v; v.f = f;
  uint32_t u = v.u;
  u += 0x7fffu + ((u >> 16) & 1u);   // round-to-nearest-even
  return (unsigned short)(u >> 16);
}
__device__ __forceinline__ float bf2f(unsigned short s) {
  union { uint32_t u; float f; } v; v.u = ((uint32_t)s) << 16;
  return v.f;
}
__device__ __forceinline__ uint32_t pkbf(float a, float b) {
  union { float f; uint32_t u; } ua, ub; ua.f = a; ub.f = b;
  return ((ua.u + 0x8000u) >> 16) | ((ub.u + 0x8000u) & 0xffff0000u);
}

// ---------------- fp32 -> bf16 convert ---------------------------------------
__global__ __launch_bounds__(256) void convert_kernel(const float* __restrict__ src,
                                                      unsigned short* __restrict__ dst,
                                                      int n) {
  int i = (blockIdx.x * 256 + threadIdx.x) * 4;
  if (i + 4 <= n) {
    float4 f = *(const float4*)(src + i);
    uint2 p;
    p.x = pkbf(f.x, f.y);
    p.y = pkbf(f.z, f.w);
    *(uint2*)(dst + i) = p;
  }
}

// ---------------- fp32 -> bf16 convert, 4 weight matrices in one dispatch ---
__global__ __launch_bounds__(256) void convert_w4(const float* __restrict__ s0,
                                                  const float* __restrict__ s1,
                                                  const float* __restrict__ s2,
                                                  const float* __restrict__ s3,
                                                  unsigned short* __restrict__ d0,
                                                  unsigned short* __restrict__ d1,
                                                  unsigned short* __restrict__ d2,
                                                  unsigned short* __restrict__ d3,
                                                  int n) {
  const int w = blockIdx.y;
  const float* src = (w == 0) ? s0 : (w == 1) ? s1 : (w == 2) ? s2 : s3;
  unsigned short* dst = (w == 0) ? d0 : (w == 1) ? d1 : (w == 2) ? d2 : d3;
  int i = (blockIdx.x * 256 + threadIdx.x) * 4;
  if (i + 4 <= n) {
    float4 f = *(const float4*)(src + i);
    uint2 p;
    p.x = pkbf(f.x, f.y);
    p.y = pkbf(f.z, f.w);
    *(uint2*)(dst + i) = p;
  }
}

// ---------------- bf16 MFMA GEMM: C = A(MxK) . B(NnxK)^T + bias -------------
// MODE 0: elu(x)+1 -> bf16 ; MODE 1: x -> bf16 ; MODE 2: x -> fp32
// M % 128 == 0, Nn % 128 == 0, K % 64 == 0, K >= 128. Block 256 (4 waves),
// tile 128x128. BK=32 double-buffered: STAGE(next) issued before COMPUTE(cur),
// one vmcnt(0)+barrier per BK=32 tile; prefetch latency hides under MFMAs.
// LDS: A0 @0, A1 @8K, B0 @16K, B1 @24K (32 KB; up to 5 blocks/CU capacity).
//
// staging: per BK=32 tile, 8 segments of 1 KB; wave w covers segs 2w,2w+1
// lane -> row = seg*16 + (lane>>2), k-short-off = (lane&3)*8
#define STAGE(BOFS, KT)                                                          \
  {                                                                              \
    _Pragma("unroll")                                                            \
    for (int r = 0; r < 2; r++) {                                                \
      const int seg = seg0 + r;                                                  \
      const int row = seg * 16 + srow;                                           \
      const unsigned short* ga = A + (arow0 + row) * (long)K + (KT) + skoff;     \
      const unsigned short* gb = B + (brow0 + row) * (long)K + (KT) + skoff;     \
      __builtin_amdgcn_global_load_lds(                                          \
          (const __attribute__((address_space(1))) void*)ga,                     \
          (__attribute__((address_space(3))) void*)(smem + (BOFS) + seg * 1024), \
          16, 0, 0);                                                             \
      __builtin_amdgcn_global_load_lds(                                          \
          (const __attribute__((address_space(1))) void*)gb,                     \
          (__attribute__((address_space(3))) void*)(smem + 16384 + (BOFS) + seg * 1024), \
          16, 0, 0);                                                             \
    }                                                                            \
  }

#define COMPUTE(BOFS)                                                            \
  {                                                                              \
    const unsigned short* Asb = (const unsigned short*)(smem + (BOFS));          \
    const unsigned short* Bsb = (const unsigned short*)(smem + 16384 + (BOFS));  \
    bf16x8 af[4], bfr[4];                                                        \
    _Pragma("unroll")                                                            \
    for (int i = 0; i < 4; i++) {                                                \
      af[i]  = *(const bf16x8*)(&Asb[(m0 + i * 16 + col) * 32 + quad * 8]);      \
      bfr[i] = *(const bf16x8*)(&Bsb[(n0 + i * 16 + col) * 32 + quad * 8]);      \
    }                                                                            \
    _Pragma("unroll")                                                            \
    for (int i = 0; i < 4; i++)                                                  \
      _Pragma("unroll")                                                          \
      for (int j = 0; j < 4; j++)                                                \
        acc[i][j] = __builtin_amdgcn_mfma_f32_16x16x32_bf16(af[i], bfr[j],       \
                                                            acc[i][j], 0, 0, 0); \
  }

template <int MODE>
__global__ __launch_bounds__(256) void gemm_bt(const unsigned short* __restrict__ A,
                                               const unsigned short* __restrict__ B,
                                               const float* __restrict__ bias,
                                               void* __restrict__ Cout,
                                               int M, int Nn, int K) {
  __shared__ __align__(16) char smem[32768];

  const int tid  = threadIdx.x;
  const int wave = tid >> 6;
  const int lane = tid & 63;
  const int col  = lane & 15;    // n (B-frag) / m (A-frag) lane index
  const int quad = lane >> 4;    // k-group for frags, row-group for C
  const int m0 = (wave >> 1) * 64;
  const int n0 = (wave & 1) * 64;
  const long arow0 = (long)blockIdx.x * 128;
  const long brow0 = (long)blockIdx.y * 128;

  // staging indices
  const int seg0  = wave * 2;
  const int srow  = lane >> 2;
  const int skoff = (lane & 3) * 8;

  // prologue: stage tile 0 into buf0 as early as possible
  STAGE(0, 0);

  const f32x4 fzero = {0.f, 0.f, 0.f, 0.f};
  f32x4 acc[4][4];
#pragma unroll
  for (int i = 0; i < 4; i++)
#pragma unroll
    for (int j = 0; j < 4; j++) acc[i][j] = fzero;

  __syncthreads();   // tile 0 resident

  // main loop: 2 BK=32 tiles per iteration, static buffer offsets.
  // Each half: issue next-tile loads, compute current tile, barrier
  // (the barrier's vmcnt(0) drain overlaps the MFMA phase just executed).
  int kt = 0;
  for (kt = 0; kt + 128 <= K; kt += 64) {
    STAGE(8192, kt + 32);
    COMPUTE(0);
    __syncthreads();
    STAGE(0, kt + 64);
    COMPUTE(8192);
    __syncthreads();
  }
  // tail: kt == K-64 here; buf0 holds tile@kt
  STAGE(8192, kt + 32);
  COMPUTE(0);
  __syncthreads();
  COMPUTE(8192);
  __syncthreads();   // LDS free for epilogue reuse

  // ---- epilogue: stage 32rows x 128cols slabs through LDS, packed stores ---
  // C/D frag layout: col = lane&15, row = quad*4 + reg.
  float bcol[4];
#pragma unroll
  for (int j = 0; j < 4; j++) bcol[j] = bias[brow0 + n0 + j * 16 + col];

  const int wp   = wave >> 1;   // wave-pair: rows m-base = wp*64
  const int lrow = tid >> 3;    // readback row 0..31
  const int cch  = tid & 7;     // readback col-chunk (16 elems each)

  if (MODE != 2) {
    unsigned short* epi = (unsigned short*)smem;
    const int EST = 136;  // shorts; 272 B row stride (16B-aligned, bank-skewed)
#pragma unroll
    for (int i = 0; i < 4; i++) {
#pragma unroll
      for (int j = 0; j < 4; j++) {
#pragma unroll
        for (int rr = 0; rr < 4; rr++) {
          float vv = acc[i][j][rr] + bcol[j];
          if (MODE == 0) vv = (vv > 0.f) ? (vv + 1.f) : __expf(vv);  // elu+1
          epi[(wp * 16 + quad * 4 + rr) * EST + n0 + j * 16 + col] = f2bf(vv);
        }
      }
      __syncthreads();
      const long gr = arow0 + (long)(lrow >> 4) * 64 + i * 16 + (lrow & 15);
      const long gc = brow0 + cch * 16;
      const unsigned short* src = &epi[lrow * EST + cch * 16];
      uint4 a  = *(const uint4*)src;
      uint4 b2 = *(const uint4*)(src + 8);
      unsigned short* Cp = (unsigned short*)Cout + gr * Nn + gc;
      *(uint4*)Cp       = a;
      *(uint4*)(Cp + 8) = b2;
      __syncthreads();
    }
  } else {
    float* epi = (float*)smem;
    const int ESF = 132;  // floats; 528 B row stride (16B-aligned, bank-skewed)
#pragma unroll
    for (int i = 0; i < 4; i++) {
#pragma unroll
      for (int j = 0; j < 4; j++) {
#pragma unroll
        for (int rr = 0; rr < 4; rr++) {
          epi[(wp * 16 + quad * 4 + rr) * ESF + n0 + j * 16 + col] =
              acc[i][j][rr] + bcol[j];
        }
      }
      __syncthreads();
      const long gr = arow0 + (long)(lrow >> 4) * 64 + i * 16 + (lrow & 15);
      const long gc = brow0 + cch * 16;
      const float* src = &epi[lrow * ESF + cch * 16];
      float* Cp = (float*)Cout + gr * Nn + gc;
#pragma unroll
      for (int s = 0; s < 4; s++)
        *(float4*)(Cp + s * 4) = *(const float4*)(src + s * 4);
      __syncthreads();
    }
  }
}

// ---------------- kv partials: kv[d][e] = sum_l kf[l][d]*v[l][e] ------------
// grid (NHG, NCHUNK), block 256. Non-atomic partial outputs per chunk.
__global__ __launch_bounds__(256) void kv_partial_kernel(const unsigned short* __restrict__ kf,
                                                         const unsigned short* __restrict__ vp,
                                                         float* __restrict__ kvp,
                                                         float* __restrict__ ksp) {
  __shared__ float ks[32 * 64];
  __shared__ float vs[32 * 64];
  const int hg = blockIdx.x;
  const int chunk = blockIdx.y;
  const int n = hg >> 4, h = hg & 15;
  const int tid = threadIdx.x;
  const int td = tid >> 4, te = tid & 15;   // thread covers d=td*4..+3, e=te*4..+3
  const long hoff = (long)n * EMB + h * HDIM;
  const int l0 = chunk * LCHUNK;

  float acc[4][4];
#pragma unroll
  for (int i = 0; i < 4; i++)
#pragma unroll
    for (int j = 0; j < 4; j++) acc[i][j] = 0.f;
  float ksacc[4] = {0.f, 0.f, 0.f, 0.f};

  const int lrow = tid >> 3;         // 0..31
  const int dcol = (tid & 7) * 8;    // 0..56

  for (int ls = 0; ls < LCHUNK; ls += 32) {
    const long g = (long)(l0 + ls + lrow) * (NBATCH * EMB) + hoff + dcol;
    uint4 kr = *(const uint4*)(kf + g);
    uint4 vr = *(const uint4*)(vp + g);
    float* kd = &ks[lrow * 64 + dcol];
    float* vd = &vs[lrow * 64 + dcol];
    uint32_t ku[4] = {kr.x, kr.y, kr.z, kr.w};
    uint32_t vu[4] = {vr.x, vr.y, vr.z, vr.w};
#pragma unroll
    for (int t2 = 0; t2 < 4; t2++) {
      kd[2 * t2]     = bf2f((unsigned short)(ku[t2] & 0xffffu));
      kd[2 * t2 + 1] = bf2f((unsigned short)(ku[t2] >> 16));
      vd[2 * t2]     = bf2f((unsigned short)(vu[t2] & 0xffffu));
      vd[2 * t2 + 1] = bf2f((unsigned short)(vu[t2] >> 16));
    }
    __syncthreads();
#pragma unroll
    for (int l = 0; l < 32; l++) {
      float kq[4], vq[4];
      *(float4*)kq = *(const float4*)(&ks[l * 64 + td * 4]);
      *(float4*)vq = *(const float4*)(&vs[l * 64 + te * 4]);
#pragma unroll
      for (int i = 0; i < 4; i++) {
        ksacc[i] += kq[i];
#pragma unroll
        for (int j = 0; j < 4; j++) acc[i][j] += kq[i] * vq[j];
      }
    }
    __syncthreads();
  }
  float* outp = kvp + ((long)chunk * NHG + hg) * 4096;
#pragma unroll
  for (int i = 0; i < 4; i++)
#pragma unroll
    for (int j = 0; j < 4; j++)
      outp[(td * 4 + i) * 64 + te * 4 + j] = acc[i][j];
  if (te == 0) {
    float* o2 = ksp + ((long)chunk * NHG + hg) * 64;
#pragma unroll
    for (int i = 0; i < 4; i++) o2[td * 4 + i] = ksacc[i];
  }
}

// ---------------- out1 = (qf @ kv) * 1/(qf.ksum + eps), bf16 row-major ------
// grid (NHG, 16), block 256. Each block: one head, 256 l-values (4 x 64).
__global__ __launch_bounds__(256) void attn_out_kernel(const unsigned short* __restrict__ qf,
                                                       const float* __restrict__ kvp,
                                                       const float* __restrict__ ksp,
                                                       unsigned short* __restrict__ out1) {
  __shared__ float kv_s[64 * 64];   // [d][e]
  __shared__ float ksum_s[64];
  __shared__ float qs[64 * 64];     // [d][l] transposed (bank-conflict-free reads)
  const int hg = blockIdx.x;
  const int lc = blockIdx.y;
  const int n = hg >> 4, h = hg & 15;
  const int tid = threadIdx.x;
  const int lane_l = tid & 63;   // l within sub-chunk
  const int eg = tid >> 6;       // wave -> e-group of 16
  const long hoff = (long)n * EMB + h * HDIM;

  // reduce kv partials into LDS
  for (int w = tid; w < 4096; w += 256) {
    float s = 0.f;
#pragma unroll
    for (int c = 0; c < NCHUNK; c++) s += kvp[((long)c * NHG + hg) * 4096 + w];
    kv_s[w] = s;
  }
  if (tid < 64) {
    float s = 0.f;
#pragma unroll
    for (int c = 0; c < NCHUNK; c++) s += ksp[((long)c * NHG + hg) * 64 + tid];
    ksum_s[tid] = s;
  }
  __syncthreads();

  const int sl = tid >> 2;           // staging l (0..63)
  const int sd0 = (tid & 3) * 16;    // staging d start

  for (int sc = 0; sc < 4; sc++) {
    const int lbase = lc * 256 + sc * 64;
    {
      const long g = (long)(lbase + sl) * (NBATCH * EMB) + hoff + sd0;
      uint4 a  = *(const uint4*)(qf + g);
      uint4 b2 = *(const uint4*)(qf + g + 8);
      uint32_t u[8] = {a.x, a.y, a.z, a.w, b2.x, b2.y, b2.z, b2.w};
#pragma unroll
      for (int t2 = 0; t2 < 8; t2++) {
        qs[(sd0 + 2 * t2) * 64 + sl]     = bf2f((unsigned short)(u[t2] & 0xffffu));
        qs[(sd0 + 2 * t2 + 1) * 64 + sl] = bf2f((unsigned short)(u[t2] >> 16));
      }
    }
    __syncthreads();

    float accv[16];
#pragma unroll
    for (int j = 0; j < 16; j++) accv[j] = 0.f;
    float denom = 0.f;
#pragma unroll 8
    for (int d = 0; d < 64; d++) {
      const float qd = qs[d * 64 + lane_l];
      denom += qd * ksum_s[d];
      const float* kvrow = &kv_s[d * 64 + eg * 16];
      float kvv[16];
      *(float4*)(kvv)      = *(const float4*)(kvrow);
      *(float4*)(kvv + 4)  = *(const float4*)(kvrow + 4);
      *(float4*)(kvv + 8)  = *(const float4*)(kvrow + 8);
      *(float4*)(kvv + 12) = *(const float4*)(kvrow + 12);
#pragma unroll
      for (int j = 0; j < 16; j++) accv[j] += qd * kvv[j];
    }
    const float z = 1.f / (denom + 1e-6f);
    const long ro = ((long)(lbase + lane_l) * NBATCH + n) * EMB + h * HDIM + eg * 16;
    uint32_t pk[8];
#pragma unroll
    for (int j = 0; j < 8; j++) {
      unsigned short lo = f2bf(accv[2 * j] * z);
      unsigned short hi = f2bf(accv[2 * j + 1] * z);
      pk[j] = (uint32_t)lo | ((uint32_t)hi << 16);
    }
    *(uint4*)(out1 + ro)     = make_uint4(pk[0], pk[1], pk[2], pk[3]);
    *(uint4*)(out1 + ro + 8) = make_uint4(pk[4], pk[5], pk[6], pk[7]);
    __syncthreads();
  }
}

// ---------------------------------------------------------------------------
extern "C" void kernel_launch(void* const* d_in, const int* in_sizes, int n_in,
                              void* d_out, int out_size, void* d_ws, size_t ws_size,
                              hipStream_t stream) {
  const float* q  = (const float*)d_in[0];
  const float* k  = (const float*)d_in[1];
  const float* v  = (const float*)d_in[2];
  const float* Wq = (const float*)d_in[3];
  const float* bq = (const float*)d_in[4];
  const float* Wk = (const float*)d_in[5];
  const float* bk = (const float*)d_in[6];
  const float* Wv = (const float*)d_in[7];
  const float* bv = (const float*)d_in[8];
  const float* Wo = (const float*)d_in[9];
  const float* bo = (const float*)d_in[10];

  char* ws = (char*)d_ws;
  const size_t BUF = (size_t)MROWS * EMB * 2;  // 33,554,432 B
  unsigned short* T0  = (unsigned short*)(ws);              // A-staging / out1
  unsigned short* qf  = (unsigned short*)(ws + BUF);
  unsigned short* kf  = (unsigned short*)(ws + 2 * BUF);
  unsigned short* vp  = (unsigned short*)(ws + 3 * BUF);
  unsigned short* Wqb = (unsigned short*)(ws + 4 * BUF);
  unsigned short* Wkb = Wqb + (size_t)EMB * EMB;
  unsigned short* Wvb = Wkb + (size_t)EMB * EMB;
  unsigned short* Wob = Wvb + (size_t)EMB * EMB;
  float* kvp = (float*)(ws + 4 * BUF + 4 * (size_t)EMB * EMB * 2);
  float* ksp = kvp + (size_t)NCHUNK * NHG * HDIM * HDIM;

  const int nQKV = MROWS * EMB;     // 16,777,216
  const int nW   = EMB * EMB;       // 1,048,576

  // all 4 weight matrices -> bf16 in one dispatch
  convert_w4<<<dim3(nW / 1024, 4), 256, 0, stream>>>(Wq, Wk, Wv, Wo,
                                                     Wqb, Wkb, Wvb, Wob, nW);

  dim3 gg(MROWS / 128, EMB / 128), bb(256);

  // projections (T0 reused as bf16 A-staging between GEMMs; stream-ordered)
  convert_kernel<<<nQKV / 1024, 256, 0, stream>>>(q, T0, nQKV);
  gemm_bt<0><<<gg, bb, 0, stream>>>(T0, Wqb, bq, qf, MROWS, EMB, EMB);
  convert_kernel<<<nQKV / 1024, 256, 0, stream>>>(k, T0, nQKV);
  gemm_bt<0><<<gg, bb, 0, stream>>>(T0, Wkb, bk, kf, MROWS, EMB, EMB);
  convert_kernel<<<nQKV / 1024, 256, 0, stream>>>(v, T0, nQKV);
  gemm_bt<1><<<gg, bb, 0, stream>>>(T0, Wvb, bv, vp, MROWS, EMB, EMB);

  // attention state + output (out1 -> T0)
  kv_partial_kernel<<<dim3(NHG, NCHUNK), 256, 0, stream>>>(kf, vp, kvp, ksp);
  attn_out_kernel<<<dim3(NHG, L_SEQ / 256), 256, 0, stream>>>(qf, kvp, ksp, T0);

  // final projection -> fp32 output
  gemm_bt<2><<<gg, bb, 0, stream>>>(T0, Wob, bo, d_out, MROWS, EMB, EMB);
}

// Round 2
// 511.034 us; speedup vs baseline: 1.0952x; 1.0631x over previous
//
#include <hip/hip_runtime.h>
#include <hip/hip_bf16.h>
#include <cstdint>

// ---------------------------------------------------------------------------
// LinearAttention on MI355X (gfx950)
// L=4096, N=4, E=1024, H=16, D=64.  M = L*N = 16384.
// Round 6: replace the 128x128 2-phase GEMM with the 256x256 8-phase template
// (T2 LDS XOR-swizzle + T3/T4 per-phase staging with counted waits + T5
// setprio). 512 threads / 8 waves (2Mx4N), BK=64, 128 KB LDS double-buffer.
// Per K-tile: 4 phases x 16 MFMA; 1 half-tile (128x64) of tile u+1 staged per
// phase into the other buffer; vmcnt(0) only at K-tile boundaries so loads
// stay in flight across barriers. Swizzle kbyte ^= ((row&7)<<4) applied on
// the global source (linear gload_lds dest, rule 21) and on ds_read addrs ->
// fragment reads at the b128 bank floor. Grid = 64x4 = 256 blocks = 1/CU.
// Epilogue: 8 slabs of 32x256 staged through LDS, packed stores.
// Other kernels unchanged.
// ---------------------------------------------------------------------------

typedef __attribute__((ext_vector_type(8))) short bf16x8;
typedef __attribute__((ext_vector_type(4))) float f32x4;

#define L_SEQ 4096
#define NBATCH 4
#define EMB 1024
#define NHEADS 16
#define HDIM 64
#define MROWS (L_SEQ * NBATCH)   // 16384
#define NHG (NBATCH * NHEADS)    // 64 head-groups
#define LCHUNK 512
#define NCHUNK (L_SEQ / LCHUNK)  // 8

__device__ __forceinline__ unsigned short f2bf(float f) {
  union { float f; uint32_t u; } v; v.f = f;
  uint32_t u = v.u;
  u += 0x7fffu + ((u >> 16) & 1u);   // round-to-nearest-even
  return (unsigned short)(u >> 16);
}
__device__ __forceinline__ float bf2f(unsigned short s) {
  union { uint32_t u; float f; } v; v.u = ((uint32_t)s) << 16;
  return v.f;
}
__device__ __forceinline__ uint32_t pkbf(float a, float b) {
  union { float f; uint32_t u; } ua, ub; ua.f = a; ub.f = b;
  return ((ua.u + 0x8000u) >> 16) | ((ub.u + 0x8000u) & 0xffff0000u);
}

// ---------------- fp32 -> bf16 convert ---------------------------------------
__global__ __launch_bounds__(256) void convert_kernel(const float* __restrict__ src,
                                                      unsigned short* __restrict__ dst,
                                                      int n) {
  int i = (blockIdx.x * 256 + threadIdx.x) * 4;
  if (i + 4 <= n) {
    float4 f = *(const float4*)(src + i);
    uint2 p;
    p.x = pkbf(f.x, f.y);
    p.y = pkbf(f.z, f.w);
    *(uint2*)(dst + i) = p;
  }
}

// ---------------- fp32 -> bf16 convert, 4 weight matrices in one dispatch ---
__global__ __launch_bounds__(256) void convert_w4(const float* __restrict__ s0,
                                                  const float* __restrict__ s1,
                                                  const float* __restrict__ s2,
                                                  const float* __restrict__ s3,
                                                  unsigned short* __restrict__ d0,
                                                  unsigned short* __restrict__ d1,
                                                  unsigned short* __restrict__ d2,
                                                  unsigned short* __restrict__ d3,
                                                  int n) {
  const int w = blockIdx.y;
  const float* src = (w == 0) ? s0 : (w == 1) ? s1 : (w == 2) ? s2 : s3;
  unsigned short* dst = (w == 0) ? d0 : (w == 1) ? d1 : (w == 2) ? d2 : d3;
  int i = (blockIdx.x * 256 + threadIdx.x) * 4;
  if (i + 4 <= n) {
    float4 f = *(const float4*)(src + i);
    uint2 p;
    p.x = pkbf(f.x, f.y);
    p.y = pkbf(f.z, f.w);
    *(uint2*)(dst + i) = p;
  }
}

// ---------------- bf16 MFMA GEMM: C = A(MxK) . B(NnxK)^T + bias -------------
// MODE 0: elu(x)+1 -> bf16 ; MODE 1: x -> bf16 ; MODE 2: x -> fp32
// M % 256 == 0, Nn % 256 == 0, K % 128 == 0 (NT even, >= 4).
// 512 threads (8 waves: wr = wid>>2 in {0,1} -> M; wc = wid&3 -> N).
// LDS: buf b at b*65536: A-tile [2 halves][128][64] bf16 @ +0, B-tile @ +32768.
// Swizzle: within a 128 B row, kbyte ^= ((row&7)<<4) (involution; applied to
// the gload_lds GLOBAL source and to ds_read addresses; LDS dest stays linear).

// stage one 128x64 half-tile (h: 0,1 = A halves; 2,3 = B halves) of K-tile at
// kshort KTN into buffer base SB. 2 gload_lds(16B) per thread.
#define STAGE_HALF(SB, H, KTN)                                                  \
  do {                                                                          \
    _Pragma("unroll")                                                           \
    for (int r_ = 0; r_ < 2; r_++) {                                            \
      const long grow_ = ((H) < 2 ? arow0 + (H) * 128 : bcol0 + ((H)-2) * 128)  \
                         + r_ * 64 + srowt;                                     \
      const unsigned short* gp_ =                                               \
          ((H) < 2 ? A : B) + grow_ * (long)K + (KTN) + skoff;                  \
      __builtin_amdgcn_global_load_lds(                                         \
          (const __attribute__((address_space(1))) void*)gp_,                   \
          (__attribute__((address_space(3))) void*)(smem + (SB) + (H) * 16384 + \
                                                    r_ * 8192 + wid * 1024),    \
          16, 0, 0);                                                            \
    }                                                                           \
  } while (0)

// one 16-MFMA cluster: C quadrant rows MFB..MFB+3 x cols NFB..NFB+1, K=64
#define MFMA_Q(AF, BF, MFB, NFB)                                                \
  do {                                                                          \
    __builtin_amdgcn_s_setprio(1);                                              \
    _Pragma("unroll")                                                           \
    for (int mi_ = 0; mi_ < 4; mi_++)                                           \
      _Pragma("unroll")                                                         \
      for (int ni_ = 0; ni_ < 2; ni_++)                                         \
        _Pragma("unroll")                                                       \
        for (int ks_ = 0; ks_ < 2; ks_++)                                       \
          acc[(MFB) + mi_][(NFB) + ni_] =                                       \
              __builtin_amdgcn_mfma_f32_16x16x32_bf16(                          \
                  AF[mi_ * 2 + ks_], BF[ni_ * 2 + ks_],                         \
                  acc[(MFB) + mi_][(NFB) + ni_], 0, 0, 0);                      \
    __builtin_amdgcn_s_setprio(0);                                              \
  } while (0)

#define PH_SYNC                                                                 \
  __builtin_amdgcn_s_barrier();                                                 \
  asm volatile("s_waitcnt lgkmcnt(0)" ::: "memory");                            \
  __builtin_amdgcn_sched_barrier(0);

// one K-tile: read from buffer RB, stage halves of next tile (kshort KTN)
// into buffer SB (iff DOSTG). 4 phases x 16 MFMA, snake (0,0)(0,1)(1,1)(1,0).
#define TILE(RB, SB, KTN, DOSTG)                                                \
  do {                                                                          \
    bf16x8 af0[8], af1[8], bf0[4], bf1[4];                                      \
    /* phase 0: read A-low + B-low; stage Ah0(next) */                          \
    _Pragma("unroll")                                                           \
    for (int mi_ = 0; mi_ < 4; mi_++)                                           \
      _Pragma("unroll")                                                         \
      for (int ks_ = 0; ks_ < 2; ks_++)                                         \
        af0[mi_ * 2 + ks_] = *(const bf16x8*)(smem + (RB) + aRowBase +          \
                                              mi_ * 2048 + akt[ks_]);           \
    _Pragma("unroll")                                                           \
    for (int ni_ = 0; ni_ < 2; ni_++)                                           \
      _Pragma("unroll")                                                         \
      for (int ks_ = 0; ks_ < 2; ks_++)                                         \
        bf0[ni_ * 2 + ks_] = *(const bf16x8*)(smem + (RB) + bRowBase +          \
                                              ni_ * 2048 + akt[ks_]);           \
    if (DOSTG) STAGE_HALF(SB, 0, KTN);                                          \
    PH_SYNC                                                                     \
    MFMA_Q(af0, bf0, 0, 0);                                                     \
    __builtin_amdgcn_s_barrier();                                               \
    /* phase 1: read B-high; stage Ah1(next) */                                 \
    _Pragma("unroll")                                                           \
    for (int ni_ = 0; ni_ < 2; ni_++)                                           \
      _Pragma("unroll")                                                         \
      for (int ks_ = 0; ks_ < 2; ks_++)                                         \
        bf1[ni_ * 2 + ks_] = *(const bf16x8*)(smem + (RB) + bRowBase +          \
                                              (ni_ + 2) * 2048 + akt[ks_]);     \
    if (DOSTG) STAGE_HALF(SB, 1, KTN);                                          \
    PH_SYNC                                                                     \
    MFMA_Q(af0, bf1, 0, 2);                                                     \
    __builtin_amdgcn_s_barrier();                                               \
    /* phase 2: read A-high; stage Bh0(next) */                                 \
    _Pragma("unroll")                                                           \
    for (int mi_ = 0; mi_ < 4; mi_++)                                           \
      _Pragma("unroll")                                                         \
      for (int ks_ = 0; ks_ < 2; ks_++)                                         \
        af1[mi_ * 2 + ks_] = *(const bf16x8*)(smem + (RB) + aRowBase +          \
                                              (mi_ + 4) * 2048 + akt[ks_]);     \
    if (DOSTG) STAGE_HALF(SB, 2, KTN);                                          \
    PH_SYNC                                                                     \
    MFMA_Q(af1, bf1, 4, 2);                                                     \
    __builtin_amdgcn_s_barrier();                                               \
    /* phase 3: no reads; stage Bh1(next); boundary vmcnt */                    \
    if (DOSTG) STAGE_HALF(SB, 3, KTN);                                          \
    PH_SYNC                                                                     \
    MFMA_Q(af1, bf0, 4, 0);                                                     \
    if (DOSTG) asm volatile("s_waitcnt vmcnt(0)" ::: "memory");                 \
    __builtin_amdgcn_s_barrier();                                               \
  } while (0)

template <int MODE>
__global__ __launch_bounds__(512, 2) void gemm_bt(const unsigned short* __restrict__ A,
                                                  const unsigned short* __restrict__ B,
                                                  const float* __restrict__ bias,
                                                  void* __restrict__ Cout,
                                                  int M, int Nn, int K) {
  __shared__ __align__(16) char smem[131072];

  const int tid   = threadIdx.x;
  const int wid   = tid >> 6;
  const int lane  = tid & 63;
  const int col16 = lane & 15;
  const int quad  = lane >> 4;
  const int wr = wid >> 2;       // 0..1 : M half (rows wr*128..+127)
  const int wc = wid & 3;        // 0..3 : N quarter (cols wc*64..+63)
  const long arow0 = (long)blockIdx.x * 256;
  const long bcol0 = (long)blockIdx.y * 256;

  // ---- read-address constants (swizzled) ----
  const int axor = (col16 & 7) << 4;
  int akt[2];
  akt[0] = (quad * 16) ^ axor;
  akt[1] = (64 + quad * 16) ^ axor;
  const int aRowBase = wr * 16384 + col16 * 128;
  const int bRowBase = 32768 + (wc >> 1) * 16384 + ((wc & 1) * 64 + col16) * 128;

  // ---- staging constants (inverse-swizzled global source) ----
  const int srowt = tid >> 3;                                   // 0..63
  const int skoff = (((tid & 7) * 16) ^ ((srowt & 7) << 4)) >> 1;  // shorts

  const int NT = K >> 6;   // K-tiles of 64 (even, >= 4)

  // prologue: stage tile 0 into buf0
  STAGE_HALF(0, 0, 0);
  STAGE_HALF(0, 1, 0);
  STAGE_HALF(0, 2, 0);
  STAGE_HALF(0, 3, 0);

  const f32x4 fzero = {0.f, 0.f, 0.f, 0.f};
  f32x4 acc[8][4];
#pragma unroll
  for (int i = 0; i < 8; i++)
#pragma unroll
    for (int j = 0; j < 4; j++) acc[i][j] = fzero;

  asm volatile("s_waitcnt vmcnt(0)" ::: "memory");
  __builtin_amdgcn_s_barrier();

  // main loop: tiles u (buf0) and u+1 (buf1); stage u+1, u+2.
#pragma unroll 1
  for (int u = 0; u + 4 <= NT; u += 2) {
    TILE(0, 65536, (u + 1) * 64, 1);
    TILE(65536, 0, (u + 2) * 64, 1);
  }
  // peel: tile NT-2 (buf0, stages NT-1), tile NT-1 (buf1, no stage)
  TILE(0, 65536, (NT - 1) * 64, 1);
  TILE(65536, 0, 0, 0);

  // ---- epilogue: 8 slabs of 32 rows x 256 cols through LDS ----
  // C/D frag: row = quad*4 + rr, col = col16 (verified layout).
  float bcol[4];
#pragma unroll
  for (int nf = 0; nf < 4; nf++) bcol[nf] = bias[bcol0 + wc * 64 + nf * 16 + col16];

  const int erow = tid >> 4;   // 0..31
  const int ecc  = tid & 15;   // 16-col chunk

  if (MODE != 2) {
    unsigned short* epi = (unsigned short*)smem;
    const int EST = 264;  // shorts; 528 B row stride (16B-aligned, bank-skewed)
#pragma unroll
    for (int s = 0; s < 8; s++) {
      if ((s >> 2) == wr) {
        const int mfb = (s & 3) * 2;
#pragma unroll
        for (int ml = 0; ml < 2; ml++)
#pragma unroll
          for (int nf = 0; nf < 4; nf++)
#pragma unroll
            for (int rr = 0; rr < 4; rr++) {
              float vv = acc[mfb + ml][nf][rr] + bcol[nf];
              if (MODE == 0) vv = (vv > 0.f) ? (vv + 1.f) : __expf(vv);  // elu+1
              epi[(ml * 16 + quad * 4 + rr) * EST + wc * 64 + nf * 16 + col16] =
                  f2bf(vv);
            }
      }
      __syncthreads();
      {
        const long gr = arow0 + s * 32 + erow;
        const unsigned short* srcp = &epi[erow * EST + ecc * 16];
        uint4 a  = *(const uint4*)srcp;
        uint4 b2 = *(const uint4*)(srcp + 8);
        unsigned short* Cp = (unsigned short*)Cout + gr * Nn + bcol0 + ecc * 16;
        *(uint4*)Cp       = a;
        *(uint4*)(Cp + 8) = b2;
      }
      __syncthreads();
    }
  } else {
    float* epi = (float*)smem;
    const int ESF = 260;  // floats; 1040 B row stride (16B-aligned, bank-skewed)
#pragma unroll
    for (int s = 0; s < 8; s++) {
      if ((s >> 2) == wr) {
        const int mfb = (s & 3) * 2;
#pragma unroll
        for (int ml = 0; ml < 2; ml++)
#pragma unroll
          for (int nf = 0; nf < 4; nf++)
#pragma unroll
            for (int rr = 0; rr < 4; rr++)
              epi[(ml * 16 + quad * 4 + rr) * ESF + wc * 64 + nf * 16 + col16] =
                  acc[mfb + ml][nf][rr] + bcol[nf];
      }
      __syncthreads();
      {
        const long gr = arow0 + s * 32 + erow;
        const float* srcp = &epi[erow * ESF + ecc * 16];
        float* Cp = (float*)Cout + gr * Nn + bcol0 + ecc * 16;
#pragma unroll
        for (int s4 = 0; s4 < 4; s4++)
          *(float4*)(Cp + s4 * 4) = *(const float4*)(srcp + s4 * 4);
      }
      __syncthreads();
    }
  }
}

// ---------------- kv partials: kv[d][e] = sum_l kf[l][d]*v[l][e] ------------
// grid (NHG, NCHUNK), block 256. Non-atomic partial outputs per chunk.
__global__ __launch_bounds__(256) void kv_partial_kernel(const unsigned short* __restrict__ kf,
                                                         const unsigned short* __restrict__ vp,
                                                         float* __restrict__ kvp,
                                                         float* __restrict__ ksp) {
  __shared__ float ks[32 * 64];
  __shared__ float vs[32 * 64];
  const int hg = blockIdx.x;
  const int chunk = blockIdx.y;
  const int n = hg >> 4, h = hg & 15;
  const int tid = threadIdx.x;
  const int td = tid >> 4, te = tid & 15;   // thread covers d=td*4..+3, e=te*4..+3
  const long hoff = (long)n * EMB + h * HDIM;
  const int l0 = chunk * LCHUNK;

  float acc[4][4];
#pragma unroll
  for (int i = 0; i < 4; i++)
#pragma unroll
    for (int j = 0; j < 4; j++) acc[i][j] = 0.f;
  float ksacc[4] = {0.f, 0.f, 0.f, 0.f};

  const int lrow = tid >> 3;         // 0..31
  const int dcol = (tid & 7) * 8;    // 0..56

  for (int ls = 0; ls < LCHUNK; ls += 32) {
    const long g = (long)(l0 + ls + lrow) * (NBATCH * EMB) + hoff + dcol;
    uint4 kr = *(const uint4*)(kf + g);
    uint4 vr = *(const uint4*)(vp + g);
    float* kd = &ks[lrow * 64 + dcol];
    float* vd = &vs[lrow * 64 + dcol];
    uint32_t ku[4] = {kr.x, kr.y, kr.z, kr.w};
    uint32_t vu[4] = {vr.x, vr.y, vr.z, vr.w};
#pragma unroll
    for (int t2 = 0; t2 < 4; t2++) {
      kd[2 * t2]     = bf2f((unsigned short)(ku[t2] & 0xffffu));
      kd[2 * t2 + 1] = bf2f((unsigned short)(ku[t2] >> 16));
      vd[2 * t2]     = bf2f((unsigned short)(vu[t2] & 0xffffu));
      vd[2 * t2 + 1] = bf2f((unsigned short)(vu[t2] >> 16));
    }
    __syncthreads();
#pragma unroll
    for (int l = 0; l < 32; l++) {
      float kq[4], vq[4];
      *(float4*)kq = *(const float4*)(&ks[l * 64 + td * 4]);
      *(float4*)vq = *(const float4*)(&vs[l * 64 + te * 4]);
#pragma unroll
      for (int i = 0; i < 4; i++) {
        ksacc[i] += kq[i];
#pragma unroll
        for (int j = 0; j < 4; j++) acc[i][j] += kq[i] * vq[j];
      }
    }
    __syncthreads();
  }
  float* outp = kvp + ((long)chunk * NHG + hg) * 4096;
#pragma unroll
  for (int i = 0; i < 4; i++)
#pragma unroll
    for (int j = 0; j < 4; j++)
      outp[(td * 4 + i) * 64 + te * 4 + j] = acc[i][j];
  if (te == 0) {
    float* o2 = ksp + ((long)chunk * NHG + hg) * 64;
#pragma unroll
    for (int i = 0; i < 4; i++) o2[td * 4 + i] = ksacc[i];
  }
}

// ---------------- out1 = (qf @ kv) * 1/(qf.ksum + eps), bf16 row-major ------
// grid (NHG, 16), block 256. Each block: one head, 256 l-values (4 x 64).
__global__ __launch_bounds__(256) void attn_out_kernel(const unsigned short* __restrict__ qf,
                                                       const float* __restrict__ kvp,
                                                       const float* __restrict__ ksp,
                                                       unsigned short* __restrict__ out1) {
  __shared__ float kv_s[64 * 64];   // [d][e]
  __shared__ float ksum_s[64];
  __shared__ float qs[64 * 64];     // [d][l] transposed (bank-conflict-free reads)
  const int hg = blockIdx.x;
  const int lc = blockIdx.y;
  const int n = hg >> 4, h = hg & 15;
  const int tid = threadIdx.x;
  const int lane_l = tid & 63;   // l within sub-chunk
  const int eg = tid >> 6;       // wave -> e-group of 16
  const long hoff = (long)n * EMB + h * HDIM;

  // reduce kv partials into LDS
  for (int w = tid; w < 4096; w += 256) {
    float s = 0.f;
#pragma unroll
    for (int c = 0; c < NCHUNK; c++) s += kvp[((long)c * NHG + hg) * 4096 + w];
    kv_s[w] = s;
  }
  if (tid < 64) {
    float s = 0.f;
#pragma unroll
    for (int c = 0; c < NCHUNK; c++) s += ksp[((long)c * NHG + hg) * 64 + tid];
    ksum_s[tid] = s;
  }
  __syncthreads();

  const int sl = tid >> 2;           // staging l (0..63)
  const int sd0 = (tid & 3) * 16;    // staging d start

  for (int sc = 0; sc < 4; sc++) {
    const int lbase = lc * 256 + sc * 64;
    {
      const long g = (long)(lbase + sl) * (NBATCH * EMB) + hoff + sd0;
      uint4 a  = *(const uint4*)(qf + g);
      uint4 b2 = *(const uint4*)(qf + g + 8);
      uint32_t u[8] = {a.x, a.y, a.z, a.w, b2.x, b2.y, b2.z, b2.w};
#pragma unroll
      for (int t2 = 0; t2 < 8; t2++) {
        qs[(sd0 + 2 * t2) * 64 + sl]     = bf2f((unsigned short)(u[t2] & 0xffffu));
        qs[(sd0 + 2 * t2 + 1) * 64 + sl] = bf2f((unsigned short)(u[t2] >> 16));
      }
    }
    __syncthreads();

    float accv[16];
#pragma unroll
    for (int j = 0; j < 16; j++) accv[j] = 0.f;
    float denom = 0.f;
#pragma unroll 8
    for (int d = 0; d < 64; d++) {
      const float qd = qs[d * 64 + lane_l];
      denom += qd * ksum_s[d];
      const float* kvrow = &kv_s[d * 64 + eg * 16];
      float kvv[16];
      *(float4*)(kvv)      = *(const float4*)(kvrow);
      *(float4*)(kvv + 4)  = *(const float4*)(kvrow + 4);
      *(float4*)(kvv + 8)  = *(const float4*)(kvrow + 8);
      *(float4*)(kvv + 12) = *(const float4*)(kvrow + 12);
#pragma unroll
      for (int j = 0; j < 16; j++) accv[j] += qd * kvv[j];
    }
    const float z = 1.f / (denom + 1e-6f);
    const long ro = ((long)(lbase + lane_l) * NBATCH + n) * EMB + h * HDIM + eg * 16;
    uint32_t pk[8];
#pragma unroll
    for (int j = 0; j < 8; j++) {
      unsigned short lo = f2bf(accv[2 * j] * z);
      unsigned short hi = f2bf(accv[2 * j + 1] * z);
      pk[j] = (uint32_t)lo | ((uint32_t)hi << 16);
    }
    *(uint4*)(out1 + ro)     = make_uint4(pk[0], pk[1], pk[2], pk[3]);
    *(uint4*)(out1 + ro + 8) = make_uint4(pk[4], pk[5], pk[6], pk[7]);
    __syncthreads();
  }
}

// ---------------------------------------------------------------------------
extern "C" void kernel_launch(void* const* d_in, const int* in_sizes, int n_in,
                              void* d_out, int out_size, void* d_ws, size_t ws_size,
                              hipStream_t stream) {
  const float* q  = (const float*)d_in[0];
  const float* k  = (const float*)d_in[1];
  const float* v  = (const float*)d_in[2];
  const float* Wq = (const float*)d_in[3];
  const float* bq = (const float*)d_in[4];
  const float* Wk = (const float*)d_in[5];
  const float* bk = (const float*)d_in[6];
  const float* Wv = (const float*)d_in[7];
  const float* bv = (const float*)d_in[8];
  const float* Wo = (const float*)d_in[9];
  const float* bo = (const float*)d_in[10];

  char* ws = (char*)d_ws;
  const size_t BUF = (size_t)MROWS * EMB * 2;  // 33,554,432 B
  unsigned short* T0  = (unsigned short*)(ws);              // A-staging / out1
  unsigned short* qf  = (unsigned short*)(ws + BUF);
  unsigned short* kf  = (unsigned short*)(ws + 2 * BUF);
  unsigned short* vp  = (unsigned short*)(ws + 3 * BUF);
  unsigned short* Wqb = (unsigned short*)(ws + 4 * BUF);
  unsigned short* Wkb = Wqb + (size_t)EMB * EMB;
  unsigned short* Wvb = Wkb + (size_t)EMB * EMB;
  unsigned short* Wob = Wvb + (size_t)EMB * EMB;
  float* kvp = (float*)(ws + 4 * BUF + 4 * (size_t)EMB * EMB * 2);
  float* ksp = kvp + (size_t)NCHUNK * NHG * HDIM * HDIM;

  const int nQKV = MROWS * EMB;     // 16,777,216
  const int nW   = EMB * EMB;       // 1,048,576

  // all 4 weight matrices -> bf16 in one dispatch
  convert_w4<<<dim3(nW / 1024, 4), 256, 0, stream>>>(Wq, Wk, Wv, Wo,
                                                     Wqb, Wkb, Wvb, Wob, nW);

  dim3 gg(MROWS / 256, EMB / 256), bb(512);

  // projections (T0 reused as bf16 A-staging between GEMMs; stream-ordered)
  convert_kernel<<<nQKV / 1024, 256, 0, stream>>>(q, T0, nQKV);
  gemm_bt<0><<<gg, bb, 0, stream>>>(T0, Wqb, bq, qf, MROWS, EMB, EMB);
  convert_kernel<<<nQKV / 1024, 256, 0, stream>>>(k, T0, nQKV);
  gemm_bt<0><<<gg, bb, 0, stream>>>(T0, Wkb, bk, kf, MROWS, EMB, EMB);
  convert_kernel<<<nQKV / 1024, 256, 0, stream>>>(v, T0, nQKV);
  gemm_bt<1><<<gg, bb, 0, stream>>>(T0, Wvb, bv, vp, MROWS, EMB, EMB);

  // attention state + output (out1 -> T0)
  kv_partial_kernel<<<dim3(NHG, NCHUNK), 256, 0, stream>>>(kf, vp, kvp, ksp);
  attn_out_kernel<<<dim3(NHG, L_SEQ / 256), 256, 0, stream>>>(qf, kvp, ksp, T0);

  // final projection -> fp32 output
  gemm_bt<2><<<gg, bb, 0, stream>>>(T0, Wob, bo, d_out, MROWS, EMB, EMB);
}

// Round 3
// 481.522 us; speedup vs baseline: 1.1623x; 1.0613x over previous
//
#include <hip/hip_runtime.h>
#include <hip/hip_bf16.h>
#include <cstdint>

// ---------------------------------------------------------------------------
// LinearAttention on MI355X (gfx950)
// L=4096, N=4, E=1024, H=16, D=64.  M = L*N = 16384.
// Round 7: MFMA-ize attn_out_kernel (was VALU outer-product at MfmaUtil=0,
// 73 us, the top dispatch). Per block: stage 256x64 qf tile via gload_lds
// (inverse-swizzled source, linear dest), build B = [kv_hi^T ; kv_lo^T ;
// ksum row] in LDS as bf16 with K=128 (hi/lo split keeps kv quantization at
// ~2^-16 rel, protecting absmax), one MFMA pass of 80 mfma_16x16x32 per wave,
// denominator via extra N-fragment + __shfl broadcast, swizzled-LDS packed
// epilogue. 8-phase 256^2 GEMM (R6) and all other kernels unchanged.
// ---------------------------------------------------------------------------

typedef __attribute__((ext_vector_type(8))) short bf16x8;
typedef __attribute__((ext_vector_type(4))) float f32x4;

#define L_SEQ 4096
#define NBATCH 4
#define EMB 1024
#define NHEADS 16
#define HDIM 64
#define MROWS (L_SEQ * NBATCH)   // 16384
#define NHG (NBATCH * NHEADS)    // 64 head-groups
#define LCHUNK 512
#define NCHUNK (L_SEQ / LCHUNK)  // 8

__device__ __forceinline__ unsigned short f2bf(float f) {
  union { float f; uint32_t u; } v; v.f = f;
  uint32_t u = v.u;
  u += 0x7fffu + ((u >> 16) & 1u);   // round-to-nearest-even
  return (unsigned short)(u >> 16);
}
__device__ __forceinline__ float bf2f(unsigned short s) {
  union { uint32_t u; float f; } v; v.u = ((uint32_t)s) << 16;
  return v.f;
}
__device__ __forceinline__ uint32_t pkbf(float a, float b) {
  union { float f; uint32_t u; } ua, ub; ua.f = a; ub.f = b;
  return ((ua.u + 0x8000u) >> 16) | ((ub.u + 0x8000u) & 0xffff0000u);
}

// ---------------- fp32 -> bf16 convert ---------------------------------------
__global__ __launch_bounds__(256) void convert_kernel(const float* __restrict__ src,
                                                      unsigned short* __restrict__ dst,
                                                      int n) {
  int i = (blockIdx.x * 256 + threadIdx.x) * 4;
  if (i + 4 <= n) {
    float4 f = *(const float4*)(src + i);
    uint2 p;
    p.x = pkbf(f.x, f.y);
    p.y = pkbf(f.z, f.w);
    *(uint2*)(dst + i) = p;
  }
}

// ---------------- fp32 -> bf16 convert, 4 weight matrices in one dispatch ---
__global__ __launch_bounds__(256) void convert_w4(const float* __restrict__ s0,
                                                  const float* __restrict__ s1,
                                                  const float* __restrict__ s2,
                                                  const float* __restrict__ s3,
                                                  unsigned short* __restrict__ d0,
                                                  unsigned short* __restrict__ d1,
                                                  unsigned short* __restrict__ d2,
                                                  unsigned short* __restrict__ d3,
                                                  int n) {
  const int w = blockIdx.y;
  const float* src = (w == 0) ? s0 : (w == 1) ? s1 : (w == 2) ? s2 : s3;
  unsigned short* dst = (w == 0) ? d0 : (w == 1) ? d1 : (w == 2) ? d2 : d3;
  int i = (blockIdx.x * 256 + threadIdx.x) * 4;
  if (i + 4 <= n) {
    float4 f = *(const float4*)(src + i);
    uint2 p;
    p.x = pkbf(f.x, f.y);
    p.y = pkbf(f.z, f.w);
    *(uint2*)(dst + i) = p;
  }
}

// ---------------- bf16 MFMA GEMM: C = A(MxK) . B(NnxK)^T + bias -------------
// MODE 0: elu(x)+1 -> bf16 ; MODE 1: x -> bf16 ; MODE 2: x -> fp32
// M % 256 == 0, Nn % 256 == 0, K % 128 == 0 (NT even, >= 4).
// 512 threads (8 waves: wr = wid>>2 in {0,1} -> M; wc = wid&3 -> N).
// LDS: buf b at b*65536: A-tile [2 halves][128][64] bf16 @ +0, B-tile @ +32768.
// Swizzle: within a 128 B row, kbyte ^= ((row&7)<<4) (involution; applied to
// the gload_lds GLOBAL source and to ds_read addresses; LDS dest stays linear).

// stage one 128x64 half-tile (h: 0,1 = A halves; 2,3 = B halves) of K-tile at
// kshort KTN into buffer base SB. 2 gload_lds(16B) per thread.
#define STAGE_HALF(SB, H, KTN)                                                  \
  do {                                                                          \
    _Pragma("unroll")                                                           \
    for (int r_ = 0; r_ < 2; r_++) {                                            \
      const long grow_ = ((H) < 2 ? arow0 + (H) * 128 : bcol0 + ((H)-2) * 128)  \
                         + r_ * 64 + srowt;                                     \
      const unsigned short* gp_ =                                               \
          ((H) < 2 ? A : B) + grow_ * (long)K + (KTN) + skoff;                  \
      __builtin_amdgcn_global_load_lds(                                         \
          (const __attribute__((address_space(1))) void*)gp_,                   \
          (__attribute__((address_space(3))) void*)(smem + (SB) + (H) * 16384 + \
                                                    r_ * 8192 + wid * 1024),    \
          16, 0, 0);                                                            \
    }                                                                           \
  } while (0)

// one 16-MFMA cluster: C quadrant rows MFB..MFB+3 x cols NFB..NFB+1, K=64
#define MFMA_Q(AF, BF, MFB, NFB)                                                \
  do {                                                                          \
    __builtin_amdgcn_s_setprio(1);                                              \
    _Pragma("unroll")                                                           \
    for (int mi_ = 0; mi_ < 4; mi_++)                                           \
      _Pragma("unroll")                                                         \
      for (int ni_ = 0; ni_ < 2; ni_++)                                         \
        _Pragma("unroll")                                                       \
        for (int ks_ = 0; ks_ < 2; ks_++)                                       \
          acc[(MFB) + mi_][(NFB) + ni_] =                                       \
              __builtin_amdgcn_mfma_f32_16x16x32_bf16(                          \
                  AF[mi_ * 2 + ks_], BF[ni_ * 2 + ks_],                         \
                  acc[(MFB) + mi_][(NFB) + ni_], 0, 0, 0);                      \
    __builtin_amdgcn_s_setprio(0);                                              \
  } while (0)

#define PH_SYNC                                                                 \
  __builtin_amdgcn_s_barrier();                                                 \
  asm volatile("s_waitcnt lgkmcnt(0)" ::: "memory");                            \
  __builtin_amdgcn_sched_barrier(0);

// one K-tile: read from buffer RB, stage halves of next tile (kshort KTN)
// into buffer SB (iff DOSTG). 4 phases x 16 MFMA, snake (0,0)(0,1)(1,1)(1,0).
#define TILE(RB, SB, KTN, DOSTG)                                                \
  do {                                                                          \
    bf16x8 af0[8], af1[8], bf0[4], bf1[4];                                      \
    /* phase 0: read A-low + B-low; stage Ah0(next) */                          \
    _Pragma("unroll")                                                           \
    for (int mi_ = 0; mi_ < 4; mi_++)                                           \
      _Pragma("unroll")                                                         \
      for (int ks_ = 0; ks_ < 2; ks_++)                                         \
        af0[mi_ * 2 + ks_] = *(const bf16x8*)(smem + (RB) + aRowBase +          \
                                              mi_ * 2048 + akt[ks_]);           \
    _Pragma("unroll")                                                           \
    for (int ni_ = 0; ni_ < 2; ni_++)                                           \
      _Pragma("unroll")                                                         \
      for (int ks_ = 0; ks_ < 2; ks_++)                                         \
        bf0[ni_ * 2 + ks_] = *(const bf16x8*)(smem + (RB) + bRowBase +          \
                                              ni_ * 2048 + akt[ks_]);           \
    if (DOSTG) STAGE_HALF(SB, 0, KTN);                                          \
    PH_SYNC                                                                     \
    MFMA_Q(af0, bf0, 0, 0);                                                     \
    __builtin_amdgcn_s_barrier();                                               \
    /* phase 1: read B-high; stage Ah1(next) */                                 \
    _Pragma("unroll")                                                           \
    for (int ni_ = 0; ni_ < 2; ni_++)                                           \
      _Pragma("unroll")                                                         \
      for (int ks_ = 0; ks_ < 2; ks_++)                                         \
        bf1[ni_ * 2 + ks_] = *(const bf16x8*)(smem + (RB) + bRowBase +          \
                                              (ni_ + 2) * 2048 + akt[ks_]);     \
    if (DOSTG) STAGE_HALF(SB, 1, KTN);                                          \
    PH_SYNC                                                                     \
    MFMA_Q(af0, bf1, 0, 2);                                                     \
    __builtin_amdgcn_s_barrier();                                               \
    /* phase 2: read A-high; stage Bh0(next) */                                 \
    _Pragma("unroll")                                                           \
    for (int mi_ = 0; mi_ < 4; mi_++)                                           \
      _Pragma("unroll")                                                         \
      for (int ks_ = 0; ks_ < 2; ks_++)                                         \
        af1[mi_ * 2 + ks_] = *(const bf16x8*)(smem + (RB) + aRowBase +          \
                                              (mi_ + 4) * 2048 + akt[ks_]);     \
    if (DOSTG) STAGE_HALF(SB, 2, KTN);                                          \
    PH_SYNC                                                                     \
    MFMA_Q(af1, bf1, 4, 2);                                                     \
    __builtin_amdgcn_s_barrier();                                               \
    /* phase 3: no reads; stage Bh1(next); boundary vmcnt */                    \
    if (DOSTG) STAGE_HALF(SB, 3, KTN);                                          \
    PH_SYNC                                                                     \
    MFMA_Q(af1, bf0, 4, 0);                                                     \
    if (DOSTG) asm volatile("s_waitcnt vmcnt(0)" ::: "memory");                 \
    __builtin_amdgcn_s_barrier();                                               \
  } while (0)

template <int MODE>
__global__ __launch_bounds__(512, 2) void gemm_bt(const unsigned short* __restrict__ A,
                                                  const unsigned short* __restrict__ B,
                                                  const float* __restrict__ bias,
                                                  void* __restrict__ Cout,
                                                  int M, int Nn, int K) {
  __shared__ __align__(16) char smem[131072];

  const int tid   = threadIdx.x;
  const int wid   = tid >> 6;
  const int lane  = tid & 63;
  const int col16 = lane & 15;
  const int quad  = lane >> 4;
  const int wr = wid >> 2;       // 0..1 : M half (rows wr*128..+127)
  const int wc = wid & 3;        // 0..3 : N quarter (cols wc*64..+63)
  const long arow0 = (long)blockIdx.x * 256;
  const long bcol0 = (long)blockIdx.y * 256;

  // ---- read-address constants (swizzled) ----
  const int axor = (col16 & 7) << 4;
  int akt[2];
  akt[0] = (quad * 16) ^ axor;
  akt[1] = (64 + quad * 16) ^ axor;
  const int aRowBase = wr * 16384 + col16 * 128;
  const int bRowBase = 32768 + (wc >> 1) * 16384 + ((wc & 1) * 64 + col16) * 128;

  // ---- staging constants (inverse-swizzled global source) ----
  const int srowt = tid >> 3;                                   // 0..63
  const int skoff = (((tid & 7) * 16) ^ ((srowt & 7) << 4)) >> 1;  // shorts

  const int NT = K >> 6;   // K-tiles of 64 (even, >= 4)

  // prologue: stage tile 0 into buf0
  STAGE_HALF(0, 0, 0);
  STAGE_HALF(0, 1, 0);
  STAGE_HALF(0, 2, 0);
  STAGE_HALF(0, 3, 0);

  const f32x4 fzero = {0.f, 0.f, 0.f, 0.f};
  f32x4 acc[8][4];
#pragma unroll
  for (int i = 0; i < 8; i++)
#pragma unroll
    for (int j = 0; j < 4; j++) acc[i][j] = fzero;

  asm volatile("s_waitcnt vmcnt(0)" ::: "memory");
  __builtin_amdgcn_s_barrier();

  // main loop: tiles u (buf0) and u+1 (buf1); stage u+1, u+2.
#pragma unroll 1
  for (int u = 0; u + 4 <= NT; u += 2) {
    TILE(0, 65536, (u + 1) * 64, 1);
    TILE(65536, 0, (u + 2) * 64, 1);
  }
  // peel: tile NT-2 (buf0, stages NT-1), tile NT-1 (buf1, no stage)
  TILE(0, 65536, (NT - 1) * 64, 1);
  TILE(65536, 0, 0, 0);

  // ---- epilogue: 8 slabs of 32 rows x 256 cols through LDS ----
  // C/D frag: row = quad*4 + rr, col = col16 (verified layout).
  float bcol[4];
#pragma unroll
  for (int nf = 0; nf < 4; nf++) bcol[nf] = bias[bcol0 + wc * 64 + nf * 16 + col16];

  const int erow = tid >> 4;   // 0..31
  const int ecc  = tid & 15;   // 16-col chunk

  if (MODE != 2) {
    unsigned short* epi = (unsigned short*)smem;
    const int EST = 264;  // shorts; 528 B row stride (16B-aligned, bank-skewed)
#pragma unroll
    for (int s = 0; s < 8; s++) {
      if ((s >> 2) == wr) {
        const int mfb = (s & 3) * 2;
#pragma unroll
        for (int ml = 0; ml < 2; ml++)
#pragma unroll
          for (int nf = 0; nf < 4; nf++)
#pragma unroll
            for (int rr = 0; rr < 4; rr++) {
              float vv = acc[mfb + ml][nf][rr] + bcol[nf];
              if (MODE == 0) vv = (vv > 0.f) ? (vv + 1.f) : __expf(vv);  // elu+1
              epi[(ml * 16 + quad * 4 + rr) * EST + wc * 64 + nf * 16 + col16] =
                  f2bf(vv);
            }
      }
      __syncthreads();
      {
        const long gr = arow0 + s * 32 + erow;
        const unsigned short* srcp = &epi[erow * EST + ecc * 16];
        uint4 a  = *(const uint4*)srcp;
        uint4 b2 = *(const uint4*)(srcp + 8);
        unsigned short* Cp = (unsigned short*)Cout + gr * Nn + bcol0 + ecc * 16;
        *(uint4*)Cp       = a;
        *(uint4*)(Cp + 8) = b2;
      }
      __syncthreads();
    }
  } else {
    float* epi = (float*)smem;
    const int ESF = 260;  // floats; 1040 B row stride (16B-aligned, bank-skewed)
#pragma unroll
    for (int s = 0; s < 8; s++) {
      if ((s >> 2) == wr) {
        const int mfb = (s & 3) * 2;
#pragma unroll
        for (int ml = 0; ml < 2; ml++)
#pragma unroll
          for (int nf = 0; nf < 4; nf++)
#pragma unroll
            for (int rr = 0; rr < 4; rr++)
              epi[(ml * 16 + quad * 4 + rr) * ESF + wc * 64 + nf * 16 + col16] =
                  acc[mfb + ml][nf][rr] + bcol[nf];
      }
      __syncthreads();
      {
        const long gr = arow0 + s * 32 + erow;
        const float* srcp = &epi[erow * ESF + ecc * 16];
        float* Cp = (float*)Cout + gr * Nn + bcol0 + ecc * 16;
#pragma unroll
        for (int s4 = 0; s4 < 4; s4++)
          *(float4*)(Cp + s4 * 4) = *(const float4*)(srcp + s4 * 4);
      }
      __syncthreads();
    }
  }
}

// ---------------- kv partials: kv[d][e] = sum_l kf[l][d]*v[l][e] ------------
// grid (NHG, NCHUNK), block 256. Non-atomic partial outputs per chunk.
__global__ __launch_bounds__(256) void kv_partial_kernel(const unsigned short* __restrict__ kf,
                                                         const unsigned short* __restrict__ vp,
                                                         float* __restrict__ kvp,
                                                         float* __restrict__ ksp) {
  __shared__ float ks[32 * 64];
  __shared__ float vs[32 * 64];
  const int hg = blockIdx.x;
  const int chunk = blockIdx.y;
  const int n = hg >> 4, h = hg & 15;
  const int tid = threadIdx.x;
  const int td = tid >> 4, te = tid & 15;   // thread covers d=td*4..+3, e=te*4..+3
  const long hoff = (long)n * EMB + h * HDIM;
  const int l0 = chunk * LCHUNK;

  float acc[4][4];
#pragma unroll
  for (int i = 0; i < 4; i++)
#pragma unroll
    for (int j = 0; j < 4; j++) acc[i][j] = 0.f;
  float ksacc[4] = {0.f, 0.f, 0.f, 0.f};

  const int lrow = tid >> 3;         // 0..31
  const int dcol = (tid & 7) * 8;    // 0..56

  for (int ls = 0; ls < LCHUNK; ls += 32) {
    const long g = (long)(l0 + ls + lrow) * (NBATCH * EMB) + hoff + dcol;
    uint4 kr = *(const uint4*)(kf + g);
    uint4 vr = *(const uint4*)(vp + g);
    float* kd = &ks[lrow * 64 + dcol];
    float* vd = &vs[lrow * 64 + dcol];
    uint32_t ku[4] = {kr.x, kr.y, kr.z, kr.w};
    uint32_t vu[4] = {vr.x, vr.y, vr.z, vr.w};
#pragma unroll
    for (int t2 = 0; t2 < 4; t2++) {
      kd[2 * t2]     = bf2f((unsigned short)(ku[t2] & 0xffffu));
      kd[2 * t2 + 1] = bf2f((unsigned short)(ku[t2] >> 16));
      vd[2 * t2]     = bf2f((unsigned short)(vu[t2] & 0xffffu));
      vd[2 * t2 + 1] = bf2f((unsigned short)(vu[t2] >> 16));
    }
    __syncthreads();
#pragma unroll
    for (int l = 0; l < 32; l++) {
      float kq[4], vq[4];
      *(float4*)kq = *(const float4*)(&ks[l * 64 + td * 4]);
      *(float4*)vq = *(const float4*)(&vs[l * 64 + te * 4]);
#pragma unroll
      for (int i = 0; i < 4; i++) {
        ksacc[i] += kq[i];
#pragma unroll
        for (int j = 0; j < 4; j++) acc[i][j] += kq[i] * vq[j];
      }
    }
    __syncthreads();
  }
  float* outp = kvp + ((long)chunk * NHG + hg) * 4096;
#pragma unroll
  for (int i = 0; i < 4; i++)
#pragma unroll
    for (int j = 0; j < 4; j++)
      outp[(td * 4 + i) * 64 + te * 4 + j] = acc[i][j];
  if (te == 0) {
    float* o2 = ksp + ((long)chunk * NHG + hg) * 64;
#pragma unroll
    for (int i = 0; i < 4; i++) o2[td * 4 + i] = ksacc[i];
  }
}

// ---------------- out1 = (qf @ kv) * 1/(qf.ksum + eps), bf16 row-major ------
// grid (NHG, 16), block 256 (4 waves). MFMA version.
// Per block: 256 l-rows x 64 e-cols for one head-group.
// LDS: A = qf tile [256 l][64 d] bf16 swizzled @0 (32 KB);
//      B = [80 n][128 k] bf16 swizzled @32768 (20 KB):
//        rows 0..63 (n=e): k 0..63 = kv_hi^T[e][d], k 64..127 = kv_lo^T[e][d]
//        row 64: k 0..63 = ksum_hi[d], k 64..127 = ksum_lo[d]; rows 65..79 = 0.
// out col 64 = qf.ksum (denominator); cols 65..79 discarded.
// Swizzle (both A and B): physical_byte = row_base + (logical_byte ^ ((row&7)<<4)).
__global__ __launch_bounds__(256) void attn_out_kernel(const unsigned short* __restrict__ qf,
                                                       const float* __restrict__ kvp,
                                                       const float* __restrict__ ksp,
                                                       unsigned short* __restrict__ out1) {
  __shared__ __align__(16) char smem[53248];
  const int hg = blockIdx.x;
  const int lc = blockIdx.y;
  const int n = hg >> 4, h = hg & 15;
  const int tid = threadIdx.x;
  const int wid = tid >> 6;
  const int lane = tid & 63;
  const int col16 = lane & 15;
  const int quad  = lane >> 4;
  const long lbase = (long)lc * 256;

  // ---- stage A = qf[lbase..+255][h*64..+63] via gload_lds (swizzled source)
#pragma unroll
  for (int r = 0; r < 8; r++) {
    const int row = r * 32 + (tid >> 3);
    const long l = lbase + row;
    const int sk = (((tid & 7) * 16) ^ ((row & 7) << 4)) >> 1;   // shorts
    const unsigned short* gp = qf + (l * NBATCH + n) * (long)EMB + h * HDIM + sk;
    __builtin_amdgcn_global_load_lds(
        (const __attribute__((address_space(1))) void*)gp,
        (__attribute__((address_space(3))) void*)(smem + r * 4096 + tid * 16),
        16, 0, 0);
  }

  // ---- build B: reduce kv partials, hi/lo split, transposed swizzled writes
  char* Bl = smem + 32768;
  for (int w = tid; w < 4096; w += 256) {
    const int d = w >> 6, e = w & 63;
    float s = 0.f;
#pragma unroll
    for (int c = 0; c < NCHUNK; c++) s += kvp[((long)c * NHG + hg) * 4096 + w];
    const unsigned short hi = f2bf(s);
    const unsigned short lo = f2bf(s - bf2f(hi));
    const int key = (e & 7) << 4;
    *(unsigned short*)(Bl + e * 256 + ((2 * d) ^ key))       = hi;
    *(unsigned short*)(Bl + e * 256 + ((128 + 2 * d) ^ key)) = lo;
  }
  if (tid < 64) {
    float s = 0.f;
#pragma unroll
    for (int c = 0; c < NCHUNK; c++) s += ksp[((long)c * NHG + hg) * 64 + tid];
    const unsigned short hi = f2bf(s);
    const unsigned short lo = f2bf(s - bf2f(hi));
    *(unsigned short*)(Bl + 64 * 256 + 2 * tid)       = hi;   // row 64: key=0
    *(unsigned short*)(Bl + 64 * 256 + 128 + 2 * tid) = lo;
  }
  {  // zero rows 65..79
    uint32_t* zb = (uint32_t*)(Bl + 65 * 256);
    for (int i = tid; i < 15 * 64; i += 256) zb[i] = 0u;
  }
  __syncthreads();

  // ---- MFMA: per wave 64 l-rows x 80 cols, logical K=128 (hi pass + lo pass)
  const int wl0 = wid * 64;
  const int akey = (col16 & 7) << 4;

  bf16x8 af[4][2];
#pragma unroll
  for (int mi = 0; mi < 4; mi++)
#pragma unroll
    for (int ks = 0; ks < 2; ks++)
      af[mi][ks] = *(const bf16x8*)(smem + (wl0 + mi * 16 + col16) * 128 +
                                    ((ks * 64 + quad * 16) ^ akey));

  const f32x4 fzero = {0.f, 0.f, 0.f, 0.f};
  f32x4 acc[4][5];
#pragma unroll
  for (int mi = 0; mi < 4; mi++)
#pragma unroll
    for (int nf = 0; nf < 5; nf++) acc[mi][nf] = fzero;

#pragma unroll
  for (int nf = 0; nf < 5; nf++) {
    bf16x8 bfr[4];
#pragma unroll
    for (int pass = 0; pass < 2; pass++)
#pragma unroll
      for (int ks = 0; ks < 2; ks++)
        bfr[pass * 2 + ks] = *(const bf16x8*)(Bl + (nf * 16 + col16) * 256 +
                                              ((pass * 128 + ks * 64 + quad * 16) ^ akey));
#pragma unroll
    for (int mi = 0; mi < 4; mi++)
#pragma unroll
      for (int pass = 0; pass < 2; pass++)
#pragma unroll
        for (int ks = 0; ks < 2; ks++)
          acc[mi][nf] = __builtin_amdgcn_mfma_f32_16x16x32_bf16(
              af[mi][ks], bfr[pass * 2 + ks], acc[mi][nf], 0, 0, 0);
  }

  __syncthreads();   // all A reads done; reuse A region as epilogue buffer

  // ---- epilogue: z from denom col (lane quad*16 holds col 64), swizzled LDS
  unsigned short* epi = (unsigned short*)smem;
#pragma unroll
  for (int mi = 0; mi < 4; mi++) {
#pragma unroll
    for (int rr = 0; rr < 4; rr++) {
      const float dv = __shfl(acc[mi][4][rr], lane & 48);
      const float z = 1.f / (dv + 1e-6f);
      const int row = wl0 + mi * 16 + quad * 4 + rr;
      const int key = (row & 7) << 4;
#pragma unroll
      for (int nf = 0; nf < 4; nf++)
        *(unsigned short*)((char*)epi + row * 128 +
                           (((nf * 16 + col16) * 2) ^ key)) =
            f2bf(acc[mi][nf][rr] * z);
    }
  }
  __syncthreads();

  // packed readback: thread -> one row chunk of 16 B per pass, 8 passes
#pragma unroll
  for (int r = 0; r < 8; r++) {
    const int row = r * 32 + (tid >> 3);
    const long l = lbase + row;
    const uint4 vv = *(const uint4*)((char*)epi + row * 128 +
                                     (((tid & 7) * 16) ^ ((row & 7) << 4)));
    *(uint4*)(out1 + (l * NBATCH + n) * (long)EMB + h * HDIM + (tid & 7) * 8) = vv;
  }
}

// ---------------------------------------------------------------------------
extern "C" void kernel_launch(void* const* d_in, const int* in_sizes, int n_in,
                              void* d_out, int out_size, void* d_ws, size_t ws_size,
                              hipStream_t stream) {
  const float* q  = (const float*)d_in[0];
  const float* k  = (const float*)d_in[1];
  const float* v  = (const float*)d_in[2];
  const float* Wq = (const float*)d_in[3];
  const float* bq = (const float*)d_in[4];
  const float* Wk = (const float*)d_in[5];
  const float* bk = (const float*)d_in[6];
  const float* Wv = (const float*)d_in[7];
  const float* bv = (const float*)d_in[8];
  const float* Wo = (const float*)d_in[9];
  const float* bo = (const float*)d_in[10];

  char* ws = (char*)d_ws;
  const size_t BUF = (size_t)MROWS * EMB * 2;  // 33,554,432 B
  unsigned short* T0  = (unsigned short*)(ws);              // A-staging / out1
  unsigned short* qf  = (unsigned short*)(ws + BUF);
  unsigned short* kf  = (unsigned short*)(ws + 2 * BUF);
  unsigned short* vp  = (unsigned short*)(ws + 3 * BUF);
  unsigned short* Wqb = (unsigned short*)(ws + 4 * BUF);
  unsigned short* Wkb = Wqb + (size_t)EMB * EMB;
  unsigned short* Wvb = Wkb + (size_t)EMB * EMB;
  unsigned short* Wob = Wvb + (size_t)EMB * EMB;
  float* kvp = (float*)(ws + 4 * BUF + 4 * (size_t)EMB * EMB * 2);
  float* ksp = kvp + (size_t)NCHUNK * NHG * HDIM * HDIM;

  const int nQKV = MROWS * EMB;     // 16,777,216
  const int nW   = EMB * EMB;       // 1,048,576

  // all 4 weight matrices -> bf16 in one dispatch
  convert_w4<<<dim3(nW / 1024, 4), 256, 0, stream>>>(Wq, Wk, Wv, Wo,
                                                     Wqb, Wkb, Wvb, Wob, nW);

  dim3 gg(MROWS / 256, EMB / 256), bb(512);

  // projections (T0 reused as bf16 A-staging between GEMMs; stream-ordered)
  convert_kernel<<<nQKV / 1024, 256, 0, stream>>>(q, T0, nQKV);
  gemm_bt<0><<<gg, bb, 0, stream>>>(T0, Wqb, bq, qf, MROWS, EMB, EMB);
  convert_kernel<<<nQKV / 1024, 256, 0, stream>>>(k, T0, nQKV);
  gemm_bt<0><<<gg, bb, 0, stream>>>(T0, Wkb, bk, kf, MROWS, EMB, EMB);
  convert_kernel<<<nQKV / 1024, 256, 0, stream>>>(v, T0, nQKV);
  gemm_bt<1><<<gg, bb, 0, stream>>>(T0, Wvb, bv, vp, MROWS, EMB, EMB);

  // attention state + output (out1 -> T0)
  kv_partial_kernel<<<dim3(NHG, NCHUNK), 256, 0, stream>>>(kf, vp, kvp, ksp);
  attn_out_kernel<<<dim3(NHG, L_SEQ / 256), 256, 0, stream>>>(qf, kvp, ksp, T0);

  // final projection -> fp32 output
  gemm_bt<2><<<gg, bb, 0, stream>>>(T0, Wob, bo, d_out, MROWS, EMB, EMB);
}

// Round 4
// 461.852 us; speedup vs baseline: 1.2118x; 1.0426x over previous
//
#include <hip/hip_runtime.h>
#include <hip/hip_bf16.h>
#include <cstdint>

// ---------------------------------------------------------------------------
// LinearAttention on MI355X (gfx950)
// L=4096, N=4, E=1024, H=16, D=64.  M = L*N = 16384.
// Round 8: true T4 counted-vmcnt pipeline in the 256x256 8-phase GEMM.
// Staging now uses 4 cycling 16KB half-tile slots per matrix (A @0, B @64K;
// slot = (2u + half) & 3) with the m201 stage stream per K-tile u:
//   ph0 -> A-hi(u+1), ph1 -> B-hi(u+1), ph2 -> B-lo(u+2), ph3 -> A-lo(u+2),
//   boundary s_waitcnt vmcnt(4)  (2 loads/stage-op; newest 2 halves in flight)
// so every half is resident 3-4 stage-ops before first consumption and the
// main loop never drains vmcnt to 0 (m218: counted-vs-drain0 = +38-73%).
// Write-safety: A-slot reads end at ph2, B-slot reads end at ph1; each
// overwrite is issued >=1 barrier later. Reads/snake/swizzle/epilogue
// unchanged from R6. attn_out (R7 MFMA version) and other kernels unchanged.
// ---------------------------------------------------------------------------

typedef __attribute__((ext_vector_type(8))) short bf16x8;
typedef __attribute__((ext_vector_type(4))) float f32x4;

#define L_SEQ 4096
#define NBATCH 4
#define EMB 1024
#define NHEADS 16
#define HDIM 64
#define MROWS (L_SEQ * NBATCH)   // 16384
#define NHG (NBATCH * NHEADS)    // 64 head-groups
#define LCHUNK 512
#define NCHUNK (L_SEQ / LCHUNK)  // 8

__device__ __forceinline__ unsigned short f2bf(float f) {
  union { float f; uint32_t u; } v; v.f = f;
  uint32_t u = v.u;
  u += 0x7fffu + ((u >> 16) & 1u);   // round-to-nearest-even
  return (unsigned short)(u >> 16);
}
__device__ __forceinline__ float bf2f(unsigned short s) {
  union { uint32_t u; float f; } v; v.u = ((uint32_t)s) << 16;
  return v.f;
}
__device__ __forceinline__ uint32_t pkbf(float a, float b) {
  union { float f; uint32_t u; } ua, ub; ua.f = a; ub.f = b;
  return ((ua.u + 0x8000u) >> 16) | ((ub.u + 0x8000u) & 0xffff0000u);
}

// ---------------- fp32 -> bf16 convert ---------------------------------------
__global__ __launch_bounds__(256) void convert_kernel(const float* __restrict__ src,
                                                      unsigned short* __restrict__ dst,
                                                      int n) {
  int i = (blockIdx.x * 256 + threadIdx.x) * 4;
  if (i + 4 <= n) {
    float4 f = *(const float4*)(src + i);
    uint2 p;
    p.x = pkbf(f.x, f.y);
    p.y = pkbf(f.z, f.w);
    *(uint2*)(dst + i) = p;
  }
}

// ---------------- fp32 -> bf16 convert, 4 weight matrices in one dispatch ---
__global__ __launch_bounds__(256) void convert_w4(const float* __restrict__ s0,
                                                  const float* __restrict__ s1,
                                                  const float* __restrict__ s2,
                                                  const float* __restrict__ s3,
                                                  unsigned short* __restrict__ d0,
                                                  unsigned short* __restrict__ d1,
                                                  unsigned short* __restrict__ d2,
                                                  unsigned short* __restrict__ d3,
                                                  int n) {
  const int w = blockIdx.y;
  const float* src = (w == 0) ? s0 : (w == 1) ? s1 : (w == 2) ? s2 : s3;
  unsigned short* dst = (w == 0) ? d0 : (w == 1) ? d1 : (w == 2) ? d2 : d3;
  int i = (blockIdx.x * 256 + threadIdx.x) * 4;
  if (i + 4 <= n) {
    float4 f = *(const float4*)(src + i);
    uint2 p;
    p.x = pkbf(f.x, f.y);
    p.y = pkbf(f.z, f.w);
    *(uint2*)(dst + i) = p;
  }
}

// ---------------- bf16 MFMA GEMM: C = A(MxK) . B(NnxK)^T + bias -------------
// MODE 0: elu(x)+1 -> bf16 ; MODE 1: x -> bf16 ; MODE 2: x -> fp32
// M % 256 == 0, Nn % 256 == 0, K % 128 == 0 (NT = K/64 even, >= 4).
// 512 threads (8 waves: wr = wid>>2 in {0,1} -> M; wc = wid&3 -> N).
// LDS: A half-slots s*16384 (s=0..3), B half-slots 65536 + s*16384 (128 KB).
// Half-tile (128 rows x 64 k) of tile u, half h lives in slot (2u+h)&3.
// Swizzle: within a 128 B row, byte ^= ((row&7)<<4) (involution; applied to
// the gload_lds GLOBAL source and to ds_read addresses; LDS dest stays linear).

// stage one 128x64 half-tile: MATB 0=A/1=B, RH row-half, SLOT, KTN k-offset.
#define STAGE_H(MATB, RH, SLOT, KTN)                                            \
  do {                                                                          \
    _Pragma("unroll")                                                           \
    for (int r_ = 0; r_ < 2; r_++) {                                            \
      const long grow_ = ((MATB) ? bcol0 : arow0) + (RH) * 128 + r_ * 64 + srowt;\
      const unsigned short* gp_ =                                               \
          ((MATB) ? B : A) + grow_ * (long)K + (KTN) + skoff;                   \
      __builtin_amdgcn_global_load_lds(                                         \
          (const __attribute__((address_space(1))) void*)gp_,                   \
          (__attribute__((address_space(3))) void*)(smem + (MATB) * 65536 +     \
              (SLOT) * 16384 + r_ * 8192 + wid * 1024),                         \
          16, 0, 0);                                                            \
    }                                                                           \
  } while (0)

// one 16-MFMA cluster: C quadrant rows MFB..MFB+3 x cols NFB..NFB+1, K=64
#define MFMA_Q(AF, BF, MFB, NFB)                                                \
  do {                                                                          \
    __builtin_amdgcn_s_setprio(1);                                              \
    _Pragma("unroll")                                                           \
    for (int mi_ = 0; mi_ < 4; mi_++)                                           \
      _Pragma("unroll")                                                         \
      for (int ni_ = 0; ni_ < 2; ni_++)                                         \
        _Pragma("unroll")                                                       \
        for (int ks_ = 0; ks_ < 2; ks_++)                                       \
          acc[(MFB) + mi_][(NFB) + ni_] =                                       \
              __builtin_amdgcn_mfma_f32_16x16x32_bf16(                          \
                  AF[mi_ * 2 + ks_], BF[ni_ * 2 + ks_],                         \
                  acc[(MFB) + mi_][(NFB) + ni_], 0, 0, 0);                      \
    __builtin_amdgcn_s_setprio(0);                                              \
  } while (0)

#define PH_SYNC                                                                 \
  __builtin_amdgcn_s_barrier();                                                 \
  asm volatile("s_waitcnt lgkmcnt(0)" ::: "memory");                            \
  __builtin_amdgcn_sched_barrier(0);

// one K-tile u (A/B lo slots at SA, hi at SA+1; SA in {0,2} = (2u)&3).
// Stages: ph0 A-hi(u+1)->slot SA^3 (iff S01), ph1 B-hi(u+1)->SA^3 (iff S01),
//         ph2 B-lo(u+2)->SA (iff S23),        ph3 A-lo(u+2)->SA (iff S23).
// VMODE: 1 = boundary vmcnt(4) (steady), 2 = vmcnt(0) (tail fill), 0 = none.
#define TILE_T(SA, K1, K2, S01, S23, VMODE)                                     \
  do {                                                                          \
    bf16x8 af0[8], af1[8], bf0[4], bf1[4];                                      \
    /* ph0: read A rows 0-63 of half wr + B rows lo; stage A-hi(u+1) */         \
    _Pragma("unroll")                                                           \
    for (int mi_ = 0; mi_ < 4; mi_++)                                           \
      _Pragma("unroll")                                                         \
      for (int ks_ = 0; ks_ < 2; ks_++)                                         \
        af0[mi_ * 2 + ks_] = *(const bf16x8*)(smem + ((SA) + wr) * 16384 + aRB +\
                                              mi_ * 2048 + akt[ks_]);           \
    _Pragma("unroll")                                                           \
    for (int ni_ = 0; ni_ < 2; ni_++)                                           \
      _Pragma("unroll")                                                         \
      for (int ks_ = 0; ks_ < 2; ks_++)                                         \
        bf0[ni_ * 2 + ks_] = *(const bf16x8*)(smem + 65536 +                    \
                                              ((SA) + (wc >> 1)) * 16384 + bRB +\
                                              ni_ * 2048 + akt[ks_]);           \
    if (S01) STAGE_H(0, 1, (SA) ^ 3, K1);                                       \
    PH_SYNC                                                                     \
    MFMA_Q(af0, bf0, 0, 0);                                                     \
    __builtin_amdgcn_s_barrier();                                               \
    /* ph1: read B rows hi; stage B-hi(u+1) */                                  \
    _Pragma("unroll")                                                           \
    for (int ni_ = 0; ni_ < 2; ni_++)                                           \
      _Pragma("unroll")                                                         \
      for (int ks_ = 0; ks_ < 2; ks_++)                                         \
        bf1[ni_ * 2 + ks_] = *(const bf16x8*)(smem + 65536 +                    \
                                              ((SA) + (wc >> 1)) * 16384 + bRB +\
                                              (ni_ + 2) * 2048 + akt[ks_]);     \
    if (S01) STAGE_H(1, 1, (SA) ^ 3, K1);                                       \
    PH_SYNC                                                                     \
    MFMA_Q(af0, bf1, 0, 2);                                                     \
    __builtin_amdgcn_s_barrier();                                               \
    /* ph2: read A rows 64-127; stage B-lo(u+2) */                              \
    _Pragma("unroll")                                                           \
    for (int mi_ = 0; mi_ < 4; mi_++)                                           \
      _Pragma("unroll")                                                         \
      for (int ks_ = 0; ks_ < 2; ks_++)                                         \
        af1[mi_ * 2 + ks_] = *(const bf16x8*)(smem + ((SA) + wr) * 16384 + aRB +\
                                              (mi_ + 4) * 2048 + akt[ks_]);     \
    if (S23) STAGE_H(1, 0, (SA), K2);                                           \
    PH_SYNC                                                                     \
    MFMA_Q(af1, bf1, 4, 2);                                                     \
    __builtin_amdgcn_s_barrier();                                               \
    /* ph3: no reads; stage A-lo(u+2); counted boundary wait */                 \
    if (S23) STAGE_H(0, 0, (SA), K2);                                           \
    PH_SYNC                                                                     \
    MFMA_Q(af1, bf0, 4, 0);                                                     \
    if ((VMODE) == 1) asm volatile("s_waitcnt vmcnt(4)" ::: "memory");          \
    if ((VMODE) == 2) asm volatile("s_waitcnt vmcnt(0)" ::: "memory");          \
    __builtin_amdgcn_s_barrier();                                               \
  } while (0)

template <int MODE>
__global__ __launch_bounds__(512, 2) void gemm_bt(const unsigned short* __restrict__ A,
                                                  const unsigned short* __restrict__ B,
                                                  const float* __restrict__ bias,
                                                  void* __restrict__ Cout,
                                                  int M, int Nn, int K) {
  __shared__ __align__(16) char smem[131072];

  const int tid   = threadIdx.x;
  const int wid   = tid >> 6;
  const int lane  = tid & 63;
  const int col16 = lane & 15;
  const int quad  = lane >> 4;
  const int wr = wid >> 2;       // 0..1 : M half (rows wr*128..+127)
  const int wc = wid & 3;        // 0..3 : N quarter (cols wc*64..+63)
  const long arow0 = (long)blockIdx.x * 256;
  const long bcol0 = (long)blockIdx.y * 256;

  // ---- read-address constants (swizzled) ----
  const int axor = (col16 & 7) << 4;
  int akt[2];
  akt[0] = (quad * 16) ^ axor;
  akt[1] = (64 + quad * 16) ^ axor;
  const int aRB = col16 * 128;                    // within-slot A row base
  const int bRB = ((wc & 1) * 64 + col16) * 128;  // within-slot B row base

  // ---- staging constants (inverse-swizzled global source) ----
  const int srowt = tid >> 3;                                   // 0..63
  const int skoff = (((tid & 7) * 16) ^ ((srowt & 7) << 4)) >> 1;  // shorts

  const int NT = K >> 6;   // K-tiles of 64 (even, >= 4)

  // prologue: tile0 all 4 halves + B-lo(1) + A-lo(1)  (6 stage-ops, 12 loads)
  STAGE_H(0, 0, 0, 0);      // A-lo(0) -> A-slot0
  STAGE_H(0, 1, 1, 0);      // A-hi(0) -> A-slot1
  STAGE_H(1, 0, 0, 0);      // B-lo(0) -> B-slot0
  STAGE_H(1, 1, 1, 0);      // B-hi(0) -> B-slot1
  STAGE_H(1, 0, 2, 64);     // B-lo(1) -> B-slot2
  STAGE_H(0, 0, 2, 64);     // A-lo(1) -> A-slot2

  const f32x4 fzero = {0.f, 0.f, 0.f, 0.f};
  f32x4 acc[8][4];
#pragma unroll
  for (int i = 0; i < 8; i++)
#pragma unroll
    for (int j = 0; j < 4; j++) acc[i][j] = fzero;

  asm volatile("s_waitcnt vmcnt(4)" ::: "memory");  // tile 0 resident
  __builtin_amdgcn_s_barrier();

  // main loop: full-stage tiles 0..NT-3 in pairs
#pragma unroll 1
  for (int u = 0; u + 4 <= NT; u += 2) {
    TILE_T(0, (u + 1) * 64, (u + 2) * 64, 1, 1, 1);
    TILE_T(2, (u + 2) * 64, (u + 3) * 64, 1, 1, 1);
  }
  // tail: tile NT-2 stages only hi-halves of NT-1; tile NT-1 stages nothing
  TILE_T(0, (NT - 1) * 64, 0, 1, 0, 2);
  TILE_T(2, 0, 0, 0, 0, 0);

  // ---- epilogue: 8 slabs of 32 rows x 256 cols through LDS ----
  // C/D frag: row = quad*4 + rr, col = col16 (verified layout).
  float bcol[4];
#pragma unroll
  for (int nf = 0; nf < 4; nf++) bcol[nf] = bias[bcol0 + wc * 64 + nf * 16 + col16];

  const int erow = tid >> 4;   // 0..31
  const int ecc  = tid & 15;   // 16-col chunk

  if (MODE != 2) {
    unsigned short* epi = (unsigned short*)smem;
    const int EST = 264;  // shorts; 528 B row stride (16B-aligned, bank-skewed)
#pragma unroll
    for (int s = 0; s < 8; s++) {
      if ((s >> 2) == wr) {
        const int mfb = (s & 3) * 2;
#pragma unroll
        for (int ml = 0; ml < 2; ml++)
#pragma unroll
          for (int nf = 0; nf < 4; nf++)
#pragma unroll
            for (int rr = 0; rr < 4; rr++) {
              float vv = acc[mfb + ml][nf][rr] + bcol[nf];
              if (MODE == 0) vv = (vv > 0.f) ? (vv + 1.f) : __expf(vv);  // elu+1
              epi[(ml * 16 + quad * 4 + rr) * EST + wc * 64 + nf * 16 + col16] =
                  f2bf(vv);
            }
      }
      __syncthreads();
      {
        const long gr = arow0 + s * 32 + erow;
        const unsigned short* srcp = &epi[erow * EST + ecc * 16];
        uint4 a  = *(const uint4*)srcp;
        uint4 b2 = *(const uint4*)(srcp + 8);
        unsigned short* Cp = (unsigned short*)Cout + gr * Nn + bcol0 + ecc * 16;
        *(uint4*)Cp       = a;
        *(uint4*)(Cp + 8) = b2;
      }
      __syncthreads();
    }
  } else {
    float* epi = (float*)smem;
    const int ESF = 260;  // floats; 1040 B row stride (16B-aligned, bank-skewed)
#pragma unroll
    for (int s = 0; s < 8; s++) {
      if ((s >> 2) == wr) {
        const int mfb = (s & 3) * 2;
#pragma unroll
        for (int ml = 0; ml < 2; ml++)
#pragma unroll
          for (int nf = 0; nf < 4; nf++)
#pragma unroll
            for (int rr = 0; rr < 4; rr++)
              epi[(ml * 16 + quad * 4 + rr) * ESF + wc * 64 + nf * 16 + col16] =
                  acc[mfb + ml][nf][rr] + bcol[nf];
      }
      __syncthreads();
      {
        const long gr = arow0 + s * 32 + erow;
        const float* srcp = &epi[erow * ESF + ecc * 16];
        float* Cp = (float*)Cout + gr * Nn + bcol0 + ecc * 16;
#pragma unroll
        for (int s4 = 0; s4 < 4; s4++)
          *(float4*)(Cp + s4 * 4) = *(const float4*)(srcp + s4 * 4);
      }
      __syncthreads();
    }
  }
}

// ---------------- kv partials: kv[d][e] = sum_l kf[l][d]*v[l][e] ------------
// grid (NHG, NCHUNK), block 256. Non-atomic partial outputs per chunk.
__global__ __launch_bounds__(256) void kv_partial_kernel(const unsigned short* __restrict__ kf,
                                                         const unsigned short* __restrict__ vp,
                                                         float* __restrict__ kvp,
                                                         float* __restrict__ ksp) {
  __shared__ float ks[32 * 64];
  __shared__ float vs[32 * 64];
  const int hg = blockIdx.x;
  const int chunk = blockIdx.y;
  const int n = hg >> 4, h = hg & 15;
  const int tid = threadIdx.x;
  const int td = tid >> 4, te = tid & 15;   // thread covers d=td*4..+3, e=te*4..+3
  const long hoff = (long)n * EMB + h * HDIM;
  const int l0 = chunk * LCHUNK;

  float acc[4][4];
#pragma unroll
  for (int i = 0; i < 4; i++)
#pragma unroll
    for (int j = 0; j < 4; j++) acc[i][j] = 0.f;
  float ksacc[4] = {0.f, 0.f, 0.f, 0.f};

  const int lrow = tid >> 3;         // 0..31
  const int dcol = (tid & 7) * 8;    // 0..56

  for (int ls = 0; ls < LCHUNK; ls += 32) {
    const long g = (long)(l0 + ls + lrow) * (NBATCH * EMB) + hoff + dcol;
    uint4 kr = *(const uint4*)(kf + g);
    uint4 vr = *(const uint4*)(vp + g);
    float* kd = &ks[lrow * 64 + dcol];
    float* vd = &vs[lrow * 64 + dcol];
    uint32_t ku[4] = {kr.x, kr.y, kr.z, kr.w};
    uint32_t vu[4] = {vr.x, vr.y, vr.z, vr.w};
#pragma unroll
    for (int t2 = 0; t2 < 4; t2++) {
      kd[2 * t2]     = bf2f((unsigned short)(ku[t2] & 0xffffu));
      kd[2 * t2 + 1] = bf2f((unsigned short)(ku[t2] >> 16));
      vd[2 * t2]     = bf2f((unsigned short)(vu[t2] & 0xffffu));
      vd[2 * t2 + 1] = bf2f((unsigned short)(vu[t2] >> 16));
    }
    __syncthreads();
#pragma unroll
    for (int l = 0; l < 32; l++) {
      float kq[4], vq[4];
      *(float4*)kq = *(const float4*)(&ks[l * 64 + td * 4]);
      *(float4*)vq = *(const float4*)(&vs[l * 64 + te * 4]);
#pragma unroll
      for (int i = 0; i < 4; i++) {
        ksacc[i] += kq[i];
#pragma unroll
        for (int j = 0; j < 4; j++) acc[i][j] += kq[i] * vq[j];
      }
    }
    __syncthreads();
  }
  float* outp = kvp + ((long)chunk * NHG + hg) * 4096;
#pragma unroll
  for (int i = 0; i < 4; i++)
#pragma unroll
    for (int j = 0; j < 4; j++)
      outp[(td * 4 + i) * 64 + te * 4 + j] = acc[i][j];
  if (te == 0) {
    float* o2 = ksp + ((long)chunk * NHG + hg) * 64;
#pragma unroll
    for (int i = 0; i < 4; i++) o2[td * 4 + i] = ksacc[i];
  }
}

// ---------------- out1 = (qf @ kv) * 1/(qf.ksum + eps), bf16 row-major ------
// grid (NHG, 16), block 256 (4 waves). MFMA version (R7).
__global__ __launch_bounds__(256) void attn_out_kernel(const unsigned short* __restrict__ qf,
                                                       const float* __restrict__ kvp,
                                                       const float* __restrict__ ksp,
                                                       unsigned short* __restrict__ out1) {
  __shared__ __align__(16) char smem[53248];
  const int hg = blockIdx.x;
  const int lc = blockIdx.y;
  const int n = hg >> 4, h = hg & 15;
  const int tid = threadIdx.x;
  const int wid = tid >> 6;
  const int lane = tid & 63;
  const int col16 = lane & 15;
  const int quad  = lane >> 4;
  const long lbase = (long)lc * 256;

  // ---- stage A = qf[lbase..+255][h*64..+63] via gload_lds (swizzled source)
#pragma unroll
  for (int r = 0; r < 8; r++) {
    const int row = r * 32 + (tid >> 3);
    const long l = lbase + row;
    const int sk = (((tid & 7) * 16) ^ ((row & 7) << 4)) >> 1;   // shorts
    const unsigned short* gp = qf + (l * NBATCH + n) * (long)EMB + h * HDIM + sk;
    __builtin_amdgcn_global_load_lds(
        (const __attribute__((address_space(1))) void*)gp,
        (__attribute__((address_space(3))) void*)(smem + r * 4096 + tid * 16),
        16, 0, 0);
  }

  // ---- build B: reduce kv partials, hi/lo split, transposed swizzled writes
  char* Bl = smem + 32768;
  for (int w = tid; w < 4096; w += 256) {
    const int d = w >> 6, e = w & 63;
    float s = 0.f;
#pragma unroll
    for (int c = 0; c < NCHUNK; c++) s += kvp[((long)c * NHG + hg) * 4096 + w];
    const unsigned short hi = f2bf(s);
    const unsigned short lo = f2bf(s - bf2f(hi));
    const int key = (e & 7) << 4;
    *(unsigned short*)(Bl + e * 256 + ((2 * d) ^ key))       = hi;
    *(unsigned short*)(Bl + e * 256 + ((128 + 2 * d) ^ key)) = lo;
  }
  if (tid < 64) {
    float s = 0.f;
#pragma unroll
    for (int c = 0; c < NCHUNK; c++) s += ksp[((long)c * NHG + hg) * 64 + tid];
    const unsigned short hi = f2bf(s);
    const unsigned short lo = f2bf(s - bf2f(hi));
    *(unsigned short*)(Bl + 64 * 256 + 2 * tid)       = hi;   // row 64: key=0
    *(unsigned short*)(Bl + 64 * 256 + 128 + 2 * tid) = lo;
  }
  {  // zero rows 65..79
    uint32_t* zb = (uint32_t*)(Bl + 65 * 256);
    for (int i = tid; i < 15 * 64; i += 256) zb[i] = 0u;
  }
  __syncthreads();

  // ---- MFMA: per wave 64 l-rows x 80 cols, logical K=128 (hi pass + lo pass)
  const int wl0 = wid * 64;
  const int akey = (col16 & 7) << 4;

  bf16x8 af[4][2];
#pragma unroll
  for (int mi = 0; mi < 4; mi++)
#pragma unroll
    for (int ks = 0; ks < 2; ks++)
      af[mi][ks] = *(const bf16x8*)(smem + (wl0 + mi * 16 + col16) * 128 +
                                    ((ks * 64 + quad * 16) ^ akey));

  const f32x4 fzero = {0.f, 0.f, 0.f, 0.f};
  f32x4 acc[4][5];
#pragma unroll
  for (int mi = 0; mi < 4; mi++)
#pragma unroll
    for (int nf = 0; nf < 5; nf++) acc[mi][nf] = fzero;

#pragma unroll
  for (int nf = 0; nf < 5; nf++) {
    bf16x8 bfr[4];
#pragma unroll
    for (int pass = 0; pass < 2; pass++)
#pragma unroll
      for (int ks = 0; ks < 2; ks++)
        bfr[pass * 2 + ks] = *(const bf16x8*)(Bl + (nf * 16 + col16) * 256 +
                                              ((pass * 128 + ks * 64 + quad * 16) ^ akey));
#pragma unroll
    for (int mi = 0; mi < 4; mi++)
#pragma unroll
      for (int pass = 0; pass < 2; pass++)
#pragma unroll
        for (int ks = 0; ks < 2; ks++)
          acc[mi][nf] = __builtin_amdgcn_mfma_f32_16x16x32_bf16(
              af[mi][ks], bfr[pass * 2 + ks], acc[mi][nf], 0, 0, 0);
  }

  __syncthreads();   // all A reads done; reuse A region as epilogue buffer

  // ---- epilogue: z from denom col (lane quad*16 holds col 64), swizzled LDS
  unsigned short* epi = (unsigned short*)smem;
#pragma unroll
  for (int mi = 0; mi < 4; mi++) {
#pragma unroll
    for (int rr = 0; rr < 4; rr++) {
      const float dv = __shfl(acc[mi][4][rr], lane & 48);
      const float z = 1.f / (dv + 1e-6f);
      const int row = wl0 + mi * 16 + quad * 4 + rr;
      const int key = (row & 7) << 4;
#pragma unroll
      for (int nf = 0; nf < 4; nf++)
        *(unsigned short*)((char*)epi + row * 128 +
                           (((nf * 16 + col16) * 2) ^ key)) =
            f2bf(acc[mi][nf][rr] * z);
    }
  }
  __syncthreads();

  // packed readback: thread -> one row chunk of 16 B per pass, 8 passes
#pragma unroll
  for (int r = 0; r < 8; r++) {
    const int row = r * 32 + (tid >> 3);
    const long l = lbase + row;
    const uint4 vv = *(const uint4*)((char*)epi + row * 128 +
                                     (((tid & 7) * 16) ^ ((row & 7) << 4)));
    *(uint4*)(out1 + (l * NBATCH + n) * (long)EMB + h * HDIM + (tid & 7) * 8) = vv;
  }
}

// ---------------------------------------------------------------------------
extern "C" void kernel_launch(void* const* d_in, const int* in_sizes, int n_in,
                              void* d_out, int out_size, void* d_ws, size_t ws_size,
                              hipStream_t stream) {
  const float* q  = (const float*)d_in[0];
  const float* k  = (const float*)d_in[1];
  const float* v  = (const float*)d_in[2];
  const float* Wq = (const float*)d_in[3];
  const float* bq = (const float*)d_in[4];
  const float* Wk = (const float*)d_in[5];
  const float* bk = (const float*)d_in[6];
  const float* Wv = (const float*)d_in[7];
  const float* bv = (const float*)d_in[8];
  const float* Wo = (const float*)d_in[9];
  const float* bo = (const float*)d_in[10];

  char* ws = (char*)d_ws;
  const size_t BUF = (size_t)MROWS * EMB * 2;  // 33,554,432 B
  unsigned short* T0  = (unsigned short*)(ws);              // A-staging / out1
  unsigned short* qf  = (unsigned short*)(ws + BUF);
  unsigned short* kf  = (unsigned short*)(ws + 2 * BUF);
  unsigned short* vp  = (unsigned short*)(ws + 3 * BUF);
  unsigned short* Wqb = (unsigned short*)(ws + 4 * BUF);
  unsigned short* Wkb = Wqb + (size_t)EMB * EMB;
  unsigned short* Wvb = Wkb + (size_t)EMB * EMB;
  unsigned short* Wob = Wvb + (size_t)EMB * EMB;
  float* kvp = (float*)(ws + 4 * BUF + 4 * (size_t)EMB * EMB * 2);
  float* ksp = kvp + (size_t)NCHUNK * NHG * HDIM * HDIM;

  const int nQKV = MROWS * EMB;     // 16,777,216
  const int nW   = EMB * EMB;       // 1,048,576

  // all 4 weight matrices -> bf16 in one dispatch
  convert_w4<<<dim3(nW / 1024, 4), 256, 0, stream>>>(Wq, Wk, Wv, Wo,
                                                     Wqb, Wkb, Wvb, Wob, nW);

  dim3 gg(MROWS / 256, EMB / 256), bb(512);

  // projections (T0 reused as bf16 A-staging between GEMMs; stream-ordered)
  convert_kernel<<<nQKV / 1024, 256, 0, stream>>>(q, T0, nQKV);
  gemm_bt<0><<<gg, bb, 0, stream>>>(T0, Wqb, bq, qf, MROWS, EMB, EMB);
  convert_kernel<<<nQKV / 1024, 256, 0, stream>>>(k, T0, nQKV);
  gemm_bt<0><<<gg, bb, 0, stream>>>(T0, Wkb, bk, kf, MROWS, EMB, EMB);
  convert_kernel<<<nQKV / 1024, 256, 0, stream>>>(v, T0, nQKV);
  gemm_bt<1><<<gg, bb, 0, stream>>>(T0, Wvb, bv, vp, MROWS, EMB, EMB);

  // attention state + output (out1 -> T0)
  kv_partial_kernel<<<dim3(NHG, NCHUNK), 256, 0, stream>>>(kf, vp, kvp, ksp);
  attn_out_kernel<<<dim3(NHG, L_SEQ / 256), 256, 0, stream>>>(qf, kvp, ksp, T0);

  // final projection -> fp32 output
  gemm_bt<2><<<gg, bb, 0, stream>>>(T0, Wob, bo, d_out, MROWS, EMB, EMB);
}